// Round 2
// baseline (1942.114 us; speedup 1.0000x reference)
//
#include <hip/hip_runtime.h>
#include <hip/hip_bf16.h>

#define N_NODES 50000
#define N_EDGES 1600000
#define ET (N_EDGES + N_NODES)
#define HID 128
#define N_LAYERS 4
#define EPS 1e-5f
#define NEG 0.2f
#define RB 256  // bn reduce blocks

__device__ __forceinline__ float wred_max(float v) {
#pragma unroll
    for (int off = 32; off; off >>= 1) v = fmaxf(v, __shfl_xor(v, off, 64));
    return v;
}
__device__ __forceinline__ float wred_sum(float v) {
#pragma unroll
    for (int off = 32; off; off >>= 1) v += __shfl_xor(v, off, 64);
    return v;
}

// ---------------- CSR build (dst-sorted), runs once per launch ----------------
__global__ void zero_deg_kernel(int* __restrict__ deg) {
    int i = blockIdx.x * 256 + threadIdx.x;
    if (i < N_NODES) deg[i] = 0;
}

__global__ void hist_kernel(const int* __restrict__ ei, int* __restrict__ deg) {
    int e = blockIdx.x * 256 + threadIdx.x;
    if (e >= ET) return;
    int dst = (e < N_EDGES) ? ei[N_EDGES + e] : (e - N_EDGES);
    atomicAdd(&deg[dst], 1);
}

__global__ void scan_kernel(const int* __restrict__ deg, int* __restrict__ rowptr,
                            int* __restrict__ cursor) {
    __shared__ int sh[1024];
    int tid = threadIdx.x;
    const int CH = 49;  // 1024*49 >= 50000
    int base = tid * CH;
    int local = 0;
    for (int i = 0; i < CH; i++) {
        int idx = base + i;
        if (idx < N_NODES) local += deg[idx];
    }
    sh[tid] = local;
    __syncthreads();
    for (int off = 1; off < 1024; off <<= 1) {
        int v = (tid >= off) ? sh[tid - off] : 0;
        __syncthreads();
        sh[tid] += v;
        __syncthreads();
    }
    int run = (tid == 0) ? 0 : sh[tid - 1];
    for (int i = 0; i < CH; i++) {
        int idx = base + i;
        if (idx < N_NODES) {
            rowptr[idx] = run;
            cursor[idx] = run;
            run += deg[idx];
        }
    }
    if (tid == 1023) rowptr[N_NODES] = sh[1023];
}

__global__ void scatter_kernel(const int* __restrict__ ei, int* __restrict__ cursor,
                               int* __restrict__ csr_src) {
    int e = blockIdx.x * 256 + threadIdx.x;
    if (e >= ET) return;
    int src, dst;
    if (e < N_EDGES) { src = ei[e]; dst = ei[N_EDGES + e]; }
    else { src = dst = e - N_EDGES; }
    int pos = atomicAdd(&cursor[dst], 1);
    csr_src[pos] = src;
}

// ---------------- GEMM: xl = h@Wl, xr = h@Wr (blockIdx.y selects) ----------------
// 64 rows/block, 256 threads, 4 rows x 8 cols per thread, H in LDS (padded),
// W streamed from global (64KB, L2-resident, broadcast across row-groups).
__global__ __launch_bounds__(256) void gemm_kernel(const float* __restrict__ hin,
                                                   const float* __restrict__ Wl,
                                                   const float* __restrict__ Wr,
                                                   float* __restrict__ xl,
                                                   float* __restrict__ xr) {
    __shared__ float Hsh[64][132];
    const float* __restrict__ W = blockIdx.y ? Wr : Wl;
    float* __restrict__ out = blockIdx.y ? xr : xl;
    int row0 = blockIdx.x * 64;
    int tid = threadIdx.x;
    for (int i = tid; i < 64 * 32; i += 256) {
        int r = i >> 5, c4 = i & 31;
        int gr = row0 + r;
        float4 v = make_float4(0.f, 0.f, 0.f, 0.f);
        if (gr < N_NODES) v = ((const float4*)(hin + (size_t)gr * HID))[c4];
        *(float4*)(&Hsh[r][c4 * 4]) = v;
    }
    __syncthreads();
    int cg = tid & 15;   // col group: cols cg*8 .. cg*8+7
    int rg = tid >> 4;   // row group: rows rg*4 .. rg*4+3
    int c0 = cg * 8;
    float4 acc[4][2];
#pragma unroll
    for (int r = 0; r < 4; r++) {
        acc[r][0] = make_float4(0.f, 0.f, 0.f, 0.f);
        acc[r][1] = make_float4(0.f, 0.f, 0.f, 0.f);
    }
#pragma unroll 8
    for (int k4 = 0; k4 < 32; k4++) {
        float4 h[4];
#pragma unroll
        for (int r = 0; r < 4; r++) h[r] = *(const float4*)(&Hsh[rg * 4 + r][k4 * 4]);
#pragma unroll
        for (int kk = 0; kk < 4; kk++) {
            int k = k4 * 4 + kk;
            float4 w0 = *(const float4*)(W + (size_t)k * HID + c0);
            float4 w1 = *(const float4*)(W + (size_t)k * HID + c0 + 4);
#pragma unroll
            for (int r = 0; r < 4; r++) {
                float hv = ((const float*)&h[r])[kk];
                acc[r][0].x += hv * w0.x; acc[r][0].y += hv * w0.y;
                acc[r][0].z += hv * w0.z; acc[r][0].w += hv * w0.w;
                acc[r][1].x += hv * w1.x; acc[r][1].y += hv * w1.y;
                acc[r][1].z += hv * w1.z; acc[r][1].w += hv * w1.w;
            }
        }
    }
#pragma unroll
    for (int r = 0; r < 4; r++) {
        int grr = row0 + rg * 4 + r;
        if (grr < N_NODES) {
            *(float4*)(out + (size_t)grr * HID + c0) = acc[r][0];
            *(float4*)(out + (size_t)grr * HID + c0 + 4) = acc[r][1];
        }
    }
}

// ---------------- Edge aggregation: wave per dst node ----------------
// Per 64-edge chunk: loop A = edge-per-lane score (no cross-lane ops),
// one amortized wave-max + wave-sum + exp per chunk, loop B = col-per-lane
// accumulate with shfl broadcast (rows are L1/L2-hot from loop A).
__global__ __launch_bounds__(256) void aggregate_kernel(
    const float* __restrict__ xl, const float* __restrict__ xr,
    const float* __restrict__ att, const float* __restrict__ bias,
    const int* __restrict__ rowptr, const int* __restrict__ csr_src,
    float* __restrict__ hout) {
    int node = blockIdx.x * 4 + (threadIdx.x >> 6);
    if (node >= N_NODES) return;
    int lane = threadIdx.x & 63;
    int c0 = lane * 2;
    int beg = rowptr[node], end = rowptr[node + 1];
    const float4* __restrict__ att4 = (const float4*)att;
    const float4* __restrict__ xr4 = (const float4*)(xr + (size_t)node * HID);
    float m = -INFINITY, s = 0.f, acc0 = 0.f, acc1 = 0.f;
    for (int base = beg; base < end; base += 64) {
        int n = end - base;
        if (n > 64) n = 64;
        int my = 0;
        float t = -INFINITY;
        if (lane < n) {
            my = csr_src[base + lane];
            const float4* __restrict__ xl4 = (const float4*)(xl + (size_t)my * HID);
            float tt = 0.f;
#pragma unroll 8
            for (int k = 0; k < 32; k++) {
                float4 v = xl4[k];
                float4 r = xr4[k];
                float4 a = att4[k];
                float s0 = v.x + r.x, s1 = v.y + r.y, s2 = v.z + r.z, s3 = v.w + r.w;
                tt += fmaxf(s0, NEG * s0) * a.x + fmaxf(s1, NEG * s1) * a.y +
                      fmaxf(s2, NEG * s2) * a.z + fmaxf(s3, NEG * s3) * a.w;
            }
            t = tt;
        }
        float mc = wred_max(t);
        float mnew = fmaxf(m, mc);
        float scale = __expf(m - mnew);  // first chunk: exp(-inf)=0 zeroes s/acc
        s *= scale; acc0 *= scale; acc1 *= scale;
        m = mnew;
        float w = __expf(t - mnew);      // invalid lanes: exp(-inf)=0
        s += wred_sum(w);
#pragma unroll 4
        for (int j = 0; j < n; j++) {
            float wj = __shfl(w, j, 64);
            int sj = __shfl(my, j, 64);
            const float2 v2 = *(const float2*)(xl + (size_t)sj * HID + c0);
            acc0 += wj * v2.x;
            acc1 += wj * v2.y;
        }
    }
    float inv = 1.f / s;
    hout[(size_t)node * HID + c0] = acc0 * inv + bias[c0];
    hout[(size_t)node * HID + c0 + 1] = acc1 * inv + bias[c0 + 1];
}

// ---------------- BatchNorm ----------------
__global__ __launch_bounds__(256) void bn_reduce_kernel(const float* __restrict__ h,
                                                        float* __restrict__ part) {
    int tid = threadIdx.x;
    int c = tid & 127, half = tid >> 7;
    float s = 0.f, q = 0.f;
    for (int r = blockIdx.x * 2 + half; r < N_NODES; r += RB * 2) {
        float v = h[(size_t)r * HID + c];
        s += v; q += v * v;
    }
    __shared__ float shs[256], shq[256];
    shs[tid] = s; shq[tid] = q;
    __syncthreads();
    if (half == 0) {
        part[blockIdx.x * 256 + c] = s + shs[tid + 128];
        part[blockIdx.x * 256 + 128 + c] = q + shq[tid + 128];
    }
}

__global__ void bn_finalize_kernel(const float* __restrict__ part, float* __restrict__ mu,
                                   float* __restrict__ rstd) {
    int c = threadIdx.x;  // 128 threads
    float s = 0.f, q = 0.f;
    for (int b = 0; b < RB; b++) {
        s += part[b * 256 + c];
        q += part[b * 256 + 128 + c];
    }
    float m = s / (float)N_NODES;
    float v = q / (float)N_NODES - m * m;
    if (v < 0.f) v = 0.f;
    mu[c] = m;
    rstd[c] = rsqrtf(v + EPS);
}

__global__ __launch_bounds__(256) void bn_norm_kernel(float* __restrict__ h,
                                                      const float* __restrict__ mu,
                                                      const float* __restrict__ rstd,
                                                      const float* __restrict__ gamma,
                                                      const float* __restrict__ beta,
                                                      float* __restrict__ acc, int first) {
    int idx = blockIdx.x * 256 + threadIdx.x;
    if (idx >= N_NODES * HID) return;
    int c = idx & 127;
    float v = (h[idx] - mu[c]) * rstd[c] * gamma[c] + beta[c];
    h[idx] = v;
    float a = 0.2f * v;  // resw = 1/(N_LAYERS+1)
    acc[idx] = first ? a : acc[idx] + a;
}

// ---------------- Decode: per-pair dot product ----------------
__global__ __launch_bounds__(256) void predict_kernel(const float* __restrict__ acc,
                                                      const int* __restrict__ eli,
                                                      float* __restrict__ out) {
    int p = blockIdx.x * 4 + (threadIdx.x >> 6);
    if (p >= 8192) return;
    int lane = threadIdx.x & 63;
    int i = eli[p], j = eli[8192 + p];
    const float2 va = *(const float2*)(acc + (size_t)i * HID + lane * 2);
    const float2 vb = *(const float2*)(acc + (size_t)j * HID + lane * 2);
    float t = va.x * vb.x + va.y * vb.y;
#pragma unroll
    for (int off = 32; off; off >>= 1) t += __shfl_xor(t, off, 64);
    if (lane == 0) out[p] = t;
}

extern "C" void kernel_launch(void* const* d_in, const int* in_sizes, int n_in,
                              void* d_out, int out_size, void* d_ws, size_t ws_size,
                              hipStream_t stream) {
    const float* x = (const float*)d_in[0];
    const int* ei = (const int*)d_in[1];
    const int* eli = (const int*)d_in[2];
    const float* Wl = (const float*)d_in[3];
    const float* Wr = (const float*)d_in[4];
    const float* att = (const float*)d_in[5];
    const float* bias = (const float*)d_in[6];
    const float* gamma = (const float*)d_in[7];
    const float* beta = (const float*)d_in[8];
    float* out = (float*)d_out;

    char* ws = (char*)d_ws;
    size_t off = 0;
    float* hbuf = (float*)(ws + off); off += (size_t)N_NODES * HID * 4;
    float* xl   = (float*)(ws + off); off += (size_t)N_NODES * HID * 4;
    float* xr   = (float*)(ws + off); off += (size_t)N_NODES * HID * 4;
    float* accb = (float*)(ws + off); off += (size_t)N_NODES * HID * 4;
    int* rowptr = (int*)(ws + off);   off += ((size_t)(N_NODES + 1) * 4 + 31) & ~31ul;
    int* deg    = (int*)(ws + off);   off += (size_t)N_NODES * 4;
    int* cursor = (int*)(ws + off);   off += (size_t)N_NODES * 4;
    int* csr_src = (int*)(ws + off);  off += (size_t)ET * 4;
    float* part = (float*)(ws + off); off += (size_t)RB * 256 * 4;
    float* mu   = (float*)(ws + off); off += 128 * 4;
    float* rstd = (float*)(ws + off); off += 128 * 4;

    // CSR build (dst-sorted); topology is fixed across layers
    zero_deg_kernel<<<(N_NODES + 255) / 256, 256, 0, stream>>>(deg);
    hist_kernel<<<(ET + 255) / 256, 256, 0, stream>>>(ei, deg);
    scan_kernel<<<1, 1024, 0, stream>>>(deg, rowptr, cursor);
    scatter_kernel<<<(ET + 255) / 256, 256, 0, stream>>>(ei, cursor, csr_src);

    for (int l = 0; l < N_LAYERS; l++) {
        const float* hin = (l == 0) ? x : hbuf;
        gemm_kernel<<<dim3((N_NODES + 63) / 64, 2), 256, 0, stream>>>(
            hin, Wl + (size_t)l * HID * HID, Wr + (size_t)l * HID * HID, xl, xr);
        aggregate_kernel<<<(N_NODES + 3) / 4, 256, 0, stream>>>(
            xl, xr, att + l * HID, bias + l * HID, rowptr, csr_src, hbuf);
        bn_reduce_kernel<<<RB, 256, 0, stream>>>(hbuf, part);
        bn_finalize_kernel<<<1, 128, 0, stream>>>(part, mu, rstd);
        bn_norm_kernel<<<(N_NODES * HID + 255) / 256, 256, 0, stream>>>(
            hbuf, mu, rstd, gamma + l * HID, beta + l * HID, accb, l == 0 ? 1 : 0);
    }
    predict_kernel<<<8192 / 4, 256, 0, stream>>>(accb, eli, out);
}

// Round 4
// 1202.093 us; speedup vs baseline: 1.6156x; 1.6156x over previous
//
#include <hip/hip_runtime.h>
#include <hip/hip_bf16.h>

#define N_NODES 50000
#define N_EDGES 1600000
#define ET (N_EDGES + N_NODES)
#define HID 128
#define N_LAYERS 4
#define EPS 1e-5f
#define NEG 0.2f
#define RB 256  // bn reduce blocks

__device__ __forceinline__ unsigned int packbf2(float a, float b) {
    unsigned int ua = __float_as_uint(a);
    ua = (ua + 0x7fffu + ((ua >> 16) & 1u)) >> 16;
    unsigned int ub = __float_as_uint(b);
    ub = (ub + 0x7fffu + ((ub >> 16) & 1u)) & 0xffff0000u;
    return (ua & 0xffffu) | ub;
}

// ---------------- CSR build (dst-sorted), runs once per launch ----------------
__global__ void zero_deg_kernel(int* __restrict__ deg) {
    int i = blockIdx.x * 256 + threadIdx.x;
    if (i < N_NODES) deg[i] = 0;
}

__global__ void hist_kernel(const int* __restrict__ ei, int* __restrict__ deg) {
    int e = blockIdx.x * 256 + threadIdx.x;
    if (e >= ET) return;
    int dst = (e < N_EDGES) ? ei[N_EDGES + e] : (e - N_EDGES);
    atomicAdd(&deg[dst], 1);
}

__global__ void scan_kernel(const int* __restrict__ deg, int* __restrict__ rowptr,
                            int* __restrict__ cursor) {
    __shared__ int sh[1024];
    int tid = threadIdx.x;
    const int CH = 49;  // 1024*49 >= 50000
    int base = tid * CH;
    int local = 0;
    for (int i = 0; i < CH; i++) {
        int idx = base + i;
        if (idx < N_NODES) local += deg[idx];
    }
    sh[tid] = local;
    __syncthreads();
    for (int off = 1; off < 1024; off <<= 1) {
        int v = (tid >= off) ? sh[tid - off] : 0;
        __syncthreads();
        sh[tid] += v;
        __syncthreads();
    }
    int run = (tid == 0) ? 0 : sh[tid - 1];
    for (int i = 0; i < CH; i++) {
        int idx = base + i;
        if (idx < N_NODES) {
            rowptr[idx] = run;
            cursor[idx] = run;
            run += deg[idx];
        }
    }
    if (tid == 1023) rowptr[N_NODES] = sh[1023];
}

__global__ void scatter_kernel(const int* __restrict__ ei, int* __restrict__ cursor,
                               int* __restrict__ csr_src) {
    int e = blockIdx.x * 256 + threadIdx.x;
    if (e >= ET) return;
    int src, dst;
    if (e < N_EDGES) { src = ei[e]; dst = ei[N_EDGES + e]; }
    else { src = dst = e - N_EDGES; }
    int pos = atomicAdd(&cursor[dst], 1);
    csr_src[pos] = src;
}

// ---------------- GEMM: y==0 -> xlb (bf16), y==1 -> xr (f32) ----------------
__global__ __launch_bounds__(256) void gemm_kernel(const float* __restrict__ hin,
                                                   const float* __restrict__ Wl,
                                                   const float* __restrict__ Wr,
                                                   unsigned int* __restrict__ xlb,
                                                   float* __restrict__ xr) {
    __shared__ float Hsh[64][132];
    const float* __restrict__ W = blockIdx.y ? Wr : Wl;
    int row0 = blockIdx.x * 64;
    int tid = threadIdx.x;
    for (int i = tid; i < 64 * 32; i += 256) {
        int r = i >> 5, c4 = i & 31;
        int gr = row0 + r;
        float4 v = make_float4(0.f, 0.f, 0.f, 0.f);
        if (gr < N_NODES) v = ((const float4*)(hin + (size_t)gr * HID))[c4];
        *(float4*)(&Hsh[r][c4 * 4]) = v;
    }
    __syncthreads();
    int cg = tid & 15;   // col group: cols cg*8 .. cg*8+7
    int rg = tid >> 4;   // row group: rows rg*4 .. rg*4+3
    int c0 = cg * 8;
    float4 acc[4][2];
#pragma unroll
    for (int r = 0; r < 4; r++) {
        acc[r][0] = make_float4(0.f, 0.f, 0.f, 0.f);
        acc[r][1] = make_float4(0.f, 0.f, 0.f, 0.f);
    }
#pragma unroll 8
    for (int k4 = 0; k4 < 32; k4++) {
        float4 h[4];
#pragma unroll
        for (int r = 0; r < 4; r++) h[r] = *(const float4*)(&Hsh[rg * 4 + r][k4 * 4]);
#pragma unroll
        for (int kk = 0; kk < 4; kk++) {
            int k = k4 * 4 + kk;
            float4 w0 = *(const float4*)(W + (size_t)k * HID + c0);
            float4 w1 = *(const float4*)(W + (size_t)k * HID + c0 + 4);
#pragma unroll
            for (int r = 0; r < 4; r++) {
                float hv = ((const float*)&h[r])[kk];
                acc[r][0].x += hv * w0.x; acc[r][0].y += hv * w0.y;
                acc[r][0].z += hv * w0.z; acc[r][0].w += hv * w0.w;
                acc[r][1].x += hv * w1.x; acc[r][1].y += hv * w1.y;
                acc[r][1].z += hv * w1.z; acc[r][1].w += hv * w1.w;
            }
        }
    }
    if (blockIdx.y == 0) {
        // bf16 row stride = 64 uints (128 bf16); this thread's 8 cols = 4 uints at cg*4
#pragma unroll
        for (int r = 0; r < 4; r++) {
            int grr = row0 + rg * 4 + r;
            if (grr < N_NODES) {
                uint4 p;
                p.x = packbf2(acc[r][0].x, acc[r][0].y);
                p.y = packbf2(acc[r][0].z, acc[r][0].w);
                p.z = packbf2(acc[r][1].x, acc[r][1].y);
                p.w = packbf2(acc[r][1].z, acc[r][1].w);
                *(uint4*)(xlb + (size_t)grr * 64 + cg * 4) = p;
            }
        }
    } else {
#pragma unroll
        for (int r = 0; r < 4; r++) {
            int grr = row0 + rg * 4 + r;
            if (grr < N_NODES) {
                *(float4*)(xr + (size_t)grr * HID + c0) = acc[r][0];
                *(float4*)(xr + (size_t)grr * HID + c0 + 4) = acc[r][1];
            }
        }
    }
}

// ---------------- Edge aggregation ----------------
// 2 nodes per wave (32 lanes/node, 4 cols/lane). Per 8-edge chunk:
// 8 independent coalesced bf16 row-gathers + per-lane partial scores (ILP),
// 8 concurrent 5-round butterfly reduces, one chunk max + rescale,
// masked exp + accumulate from registers (xl read exactly once per edge).
__global__ __launch_bounds__(256) void aggregate_kernel(
    const unsigned int* __restrict__ xlb, const float* __restrict__ xr,
    const float* __restrict__ att, const float* __restrict__ bias,
    const int* __restrict__ rowptr, const int* __restrict__ csr_src,
    float* __restrict__ hout) {
    int node = blockIdx.x * 8 + (threadIdx.x >> 5);
    if (node >= N_NODES) return;
    int hl = threadIdx.x & 31;   // lane within half-wave
    int c0 = hl * 4;             // 4 columns per lane
    const float4 a4 = *(const float4*)(att + c0);
    const float4 r4 = *(const float4*)(xr + (size_t)node * HID + c0);
    int beg = rowptr[node], end = rowptr[node + 1];
    float m = -INFINITY, s = 0.f;
    float4 acc = make_float4(0.f, 0.f, 0.f, 0.f);
    for (int base = beg; base < end; base += 8) {
        int nn = end - base;
        if (nn > 8) nn = 8;
        int idx8 = csr_src[min(base + (hl & 7), end - 1)];
        uint2 v[8];
        float p[8];
#pragma unroll
        for (int j = 0; j < 8; j++) {
            int sj = __shfl(idx8, j, 32);
            v[j] = *(const uint2*)(xlb + (size_t)sj * 64 + hl * 2);  // row stride 64 uints
            float v0 = __uint_as_float(v[j].x << 16);
            float v1 = __uint_as_float(v[j].x & 0xffff0000u);
            float v2 = __uint_as_float(v[j].y << 16);
            float v3 = __uint_as_float(v[j].y & 0xffff0000u);
            float s0 = v0 + r4.x, s1 = v1 + r4.y, s2 = v2 + r4.z, s3 = v3 + r4.w;
            p[j] = fmaxf(s0, NEG * s0) * a4.x + fmaxf(s1, NEG * s1) * a4.y +
                   fmaxf(s2, NEG * s2) * a4.z + fmaxf(s3, NEG * s3) * a4.w;
        }
        // 8 concurrent butterfly sums over the 32-lane half
#pragma unroll
        for (int off = 1; off <= 16; off <<= 1) {
#pragma unroll
            for (int j = 0; j < 8; j++) p[j] += __shfl_xor(p[j], off, 32);
        }
#pragma unroll
        for (int j = 0; j < 8; j++)
            if (j >= nn) p[j] = -INFINITY;
        float mc = fmaxf(fmaxf(fmaxf(p[0], p[1]), fmaxf(p[2], p[3])),
                         fmaxf(fmaxf(p[4], p[5]), fmaxf(p[6], p[7])));
        float mnew = fmaxf(m, mc);
        float scale = __expf(m - mnew);  // first chunk: exp(-inf)=0
        s *= scale;
        acc.x *= scale; acc.y *= scale; acc.z *= scale; acc.w *= scale;
        m = mnew;
#pragma unroll
        for (int j = 0; j < 8; j++) {
            float w = __expf(p[j] - mnew);  // masked j: exp(-inf)=0
            s += w;
            float v0 = __uint_as_float(v[j].x << 16);
            float v1 = __uint_as_float(v[j].x & 0xffff0000u);
            float v2 = __uint_as_float(v[j].y << 16);
            float v3 = __uint_as_float(v[j].y & 0xffff0000u);
            acc.x += w * v0; acc.y += w * v1; acc.z += w * v2; acc.w += w * v3;
        }
    }
    float inv = 1.f / s;
    const float4 b4 = *(const float4*)(bias + c0);
    float4 o;
    o.x = acc.x * inv + b4.x; o.y = acc.y * inv + b4.y;
    o.z = acc.z * inv + b4.z; o.w = acc.w * inv + b4.w;
    *(float4*)(hout + (size_t)node * HID + c0) = o;
}

// ---------------- BatchNorm ----------------
__global__ __launch_bounds__(256) void bn_reduce_kernel(const float* __restrict__ h,
                                                        float* __restrict__ part) {
    int tid = threadIdx.x;
    int c = tid & 127, half = tid >> 7;
    float s = 0.f, q = 0.f;
    for (int r = blockIdx.x * 2 + half; r < N_NODES; r += RB * 2) {
        float v = h[(size_t)r * HID + c];
        s += v; q += v * v;
    }
    __shared__ float shs[256], shq[256];
    shs[tid] = s; shq[tid] = q;
    __syncthreads();
    if (half == 0) {
        part[blockIdx.x * 256 + c] = s + shs[tid + 128];
        part[blockIdx.x * 256 + 128 + c] = q + shq[tid + 128];
    }
}

__global__ void bn_finalize_kernel(const float* __restrict__ part, float* __restrict__ mu,
                                   float* __restrict__ rstd) {
    int c = threadIdx.x;  // 128 threads
    float s = 0.f, q = 0.f;
    for (int b = 0; b < RB; b++) {
        s += part[b * 256 + c];
        q += part[b * 256 + 128 + c];
    }
    float m = s / (float)N_NODES;
    float v = q / (float)N_NODES - m * m;
    if (v < 0.f) v = 0.f;
    mu[c] = m;
    rstd[c] = rsqrtf(v + EPS);
}

__global__ __launch_bounds__(256) void bn_norm_kernel(float* __restrict__ h,
                                                      const float* __restrict__ mu,
                                                      const float* __restrict__ rstd,
                                                      const float* __restrict__ gamma,
                                                      const float* __restrict__ beta,
                                                      float* __restrict__ acc, int first) {
    int idx = blockIdx.x * 256 + threadIdx.x;
    if (idx >= N_NODES * HID) return;
    int c = idx & 127;
    float v = (h[idx] - mu[c]) * rstd[c] * gamma[c] + beta[c];
    h[idx] = v;
    float a = 0.2f * v;  // resw = 1/(N_LAYERS+1)
    acc[idx] = first ? a : acc[idx] + a;
}

// ---------------- Decode: per-pair dot product ----------------
__global__ __launch_bounds__(256) void predict_kernel(const float* __restrict__ acc,
                                                      const int* __restrict__ eli,
                                                      float* __restrict__ out) {
    int p = blockIdx.x * 4 + (threadIdx.x >> 6);
    if (p >= 8192) return;
    int lane = threadIdx.x & 63;
    int i = eli[p], j = eli[8192 + p];
    const float2 va = *(const float2*)(acc + (size_t)i * HID + lane * 2);
    const float2 vb = *(const float2*)(acc + (size_t)j * HID + lane * 2);
    float t = va.x * vb.x + va.y * vb.y;
#pragma unroll
    for (int off = 32; off; off >>= 1) t += __shfl_xor(t, off, 64);
    if (lane == 0) out[p] = t;
}

extern "C" void kernel_launch(void* const* d_in, const int* in_sizes, int n_in,
                              void* d_out, int out_size, void* d_ws, size_t ws_size,
                              hipStream_t stream) {
    const float* x = (const float*)d_in[0];
    const int* ei = (const int*)d_in[1];
    const int* eli = (const int*)d_in[2];
    const float* Wl = (const float*)d_in[3];
    const float* Wr = (const float*)d_in[4];
    const float* att = (const float*)d_in[5];
    const float* bias = (const float*)d_in[6];
    const float* gamma = (const float*)d_in[7];
    const float* beta = (const float*)d_in[8];
    float* out = (float*)d_out;

    char* ws = (char*)d_ws;
    size_t off = 0;
    float* hbuf = (float*)(ws + off); off += (size_t)N_NODES * HID * 4;
    float* xr   = (float*)(ws + off); off += (size_t)N_NODES * HID * 4;
    float* accb = (float*)(ws + off); off += (size_t)N_NODES * HID * 4;
    unsigned int* xlb = (unsigned int*)(ws + off); off += (size_t)N_NODES * HID * 2;  // bf16
    int* rowptr = (int*)(ws + off);   off += ((size_t)(N_NODES + 1) * 4 + 31) & ~31ul;
    int* deg    = (int*)(ws + off);   off += (size_t)N_NODES * 4;
    int* cursor = (int*)(ws + off);   off += (size_t)N_NODES * 4;
    int* csr_src = (int*)(ws + off);  off += (size_t)(ET + 8) * 4;
    float* part = (float*)(ws + off); off += (size_t)RB * 256 * 4;
    float* mu   = (float*)(ws + off); off += 128 * 4;
    float* rstd = (float*)(ws + off); off += 128 * 4;

    // CSR build (dst-sorted); topology is fixed across layers
    zero_deg_kernel<<<(N_NODES + 255) / 256, 256, 0, stream>>>(deg);
    hist_kernel<<<(ET + 255) / 256, 256, 0, stream>>>(ei, deg);
    scan_kernel<<<1, 1024, 0, stream>>>(deg, rowptr, cursor);
    scatter_kernel<<<(ET + 255) / 256, 256, 0, stream>>>(ei, cursor, csr_src);

    for (int l = 0; l < N_LAYERS; l++) {
        const float* hin = (l == 0) ? x : hbuf;
        gemm_kernel<<<dim3((N_NODES + 63) / 64, 2), 256, 0, stream>>>(
            hin, Wl + (size_t)l * HID * HID, Wr + (size_t)l * HID * HID, xlb, xr);
        aggregate_kernel<<<(N_NODES + 7) / 8, 256, 0, stream>>>(
            xlb, xr, att + l * HID, bias + l * HID, rowptr, csr_src, hbuf);
        bn_reduce_kernel<<<RB, 256, 0, stream>>>(hbuf, part);
        bn_finalize_kernel<<<1, 128, 0, stream>>>(part, mu, rstd);
        bn_norm_kernel<<<(N_NODES * HID + 255) / 256, 256, 0, stream>>>(
            hbuf, mu, rstd, gamma + l * HID, beta + l * HID, accb, l == 0 ? 1 : 0);
    }
    predict_kernel<<<8192 / 4, 256, 0, stream>>>(accb, eli, out);
}

// Round 5
// 919.095 us; speedup vs baseline: 2.1131x; 1.3079x over previous
//
#include <hip/hip_runtime.h>
#include <hip/hip_bf16.h>

#define N_NODES 50000
#define N_EDGES 1600000
#define ET (N_EDGES + N_NODES)
#define HID 128
#define N_LAYERS 4
#define EPS 1e-5f
#define NEG 0.2f
#define RB 256     // bn reduce blocks
#define NBUCK 782  // ceil(N_NODES/64)
#define BCHUNK 8192

__device__ __forceinline__ unsigned int packbf2(float a, float b) {
    unsigned int ua = __float_as_uint(a);
    ua = (ua + 0x7fffu + ((ua >> 16) & 1u)) >> 16;
    unsigned int ub = __float_as_uint(b);
    ub = (ub + 0x7fffu + ((ub >> 16) & 1u)) & 0xffff0000u;
    return (ua & 0xffffu) | ub;
}

// ---------------- CSR build: two-level bucketed counting sort ----------------
// Buckets of 64 nodes. Writes cluster into bucket-contiguous regions so L2
// coalesces them (vs. 64B-line-per-4B-write inflation of the naive scatter).
__global__ void bucket_zero_kernel(int* __restrict__ gcnt) {
    int i = blockIdx.x * 256 + threadIdx.x;
    if (i < NBUCK) gcnt[i] = 0;
}

__global__ __launch_bounds__(256) void bucket_hist_kernel(const int* __restrict__ ei,
                                                          int* __restrict__ gcnt) {
    __shared__ int h[NBUCK];
    for (int i = threadIdx.x; i < NBUCK; i += 256) h[i] = 0;
    __syncthreads();
    int base = blockIdx.x * BCHUNK;
    int lim = min(base + BCHUNK, ET);
    for (int i = base + threadIdx.x; i < lim; i += 256) {
        int dst = (i < N_EDGES) ? ei[N_EDGES + i] : i - N_EDGES;
        atomicAdd(&h[dst >> 6], 1);
    }
    __syncthreads();
    for (int i = threadIdx.x; i < NBUCK; i += 256)
        if (h[i]) atomicAdd(&gcnt[i], h[i]);
}

__global__ void bucket_scan_kernel(const int* __restrict__ gcnt, int* __restrict__ bbase,
                                   int* __restrict__ bcur, int* __restrict__ rowptr) {
    __shared__ int sh[1024];
    int tid = threadIdx.x;
    int v = (tid < NBUCK) ? gcnt[tid] : 0;
    sh[tid] = v;
    __syncthreads();
    for (int off = 1; off < 1024; off <<= 1) {
        int t = (tid >= off) ? sh[tid - off] : 0;
        __syncthreads();
        sh[tid] += t;
        __syncthreads();
    }
    if (tid < NBUCK) {
        int ex = sh[tid] - v;
        bbase[tid] = ex;
        bcur[tid] = ex;
    }
    if (tid == NBUCK - 1) bbase[NBUCK] = sh[tid];
    if (tid == 0) rowptr[N_NODES] = ET;
}

__global__ __launch_bounds__(256) void bucket_scatter_kernel(const int* __restrict__ ei,
                                                             int* __restrict__ bcur,
                                                             unsigned int* __restrict__ pairs) {
    __shared__ int h[NBUCK];
    __shared__ int rbase[NBUCK];
    for (int i = threadIdx.x; i < NBUCK; i += 256) h[i] = 0;
    __syncthreads();
    int base = blockIdx.x * BCHUNK;
    int lim = min(base + BCHUNK, ET);
    for (int i = base + threadIdx.x; i < lim; i += 256) {
        int dst = (i < N_EDGES) ? ei[N_EDGES + i] : i - N_EDGES;
        atomicAdd(&h[dst >> 6], 1);
    }
    __syncthreads();
    for (int i = threadIdx.x; i < NBUCK; i += 256) {
        rbase[i] = h[i] ? atomicAdd(&bcur[i], h[i]) : 0;
        h[i] = 0;
    }
    __syncthreads();
    for (int i = base + threadIdx.x; i < lim; i += 256) {
        int src, dst;
        if (i < N_EDGES) { src = ei[i]; dst = ei[N_EDGES + i]; }
        else { src = dst = i - N_EDGES; }
        int b = dst >> 6;
        int pos = rbase[b] + atomicAdd(&h[b], 1);
        pairs[pos] = (unsigned int)src | ((unsigned int)(dst & 63) << 16);  // src < 2^16... N_NODES=50000 < 65536
    }
}

__global__ __launch_bounds__(256) void bucket_sort_kernel(const unsigned int* __restrict__ pairs,
                                                          const int* __restrict__ bbase,
                                                          int* __restrict__ rowptr,
                                                          int* __restrict__ csr_src) {
    __shared__ int h[64], ex[64], cur[64];
    int b = blockIdx.x;
    int tid = threadIdx.x;
    if (tid < 64) h[tid] = 0;
    __syncthreads();
    int bs = bbase[b], be = bbase[b + 1];
    for (int i = bs + tid; i < be; i += 256) atomicAdd(&h[pairs[i] >> 16], 1);
    __syncthreads();
    if (tid == 0) {
        int run = 0;
        for (int k = 0; k < 64; k++) { ex[k] = run; cur[k] = run; run += h[k]; }
    }
    __syncthreads();
    int n0 = b * 64;
    if (tid < 64 && n0 + tid < N_NODES) rowptr[n0 + tid] = bs + ex[tid];
    for (int i = bs + tid; i < be; i += 256) {
        unsigned int u = pairs[i];
        int ln = u >> 16;
        int pos = bs + atomicAdd(&cur[ln], 1);
        csr_src[pos] = (int)(u & 0xffffu);
    }
}

// ---------------- GEMM: y==0 -> xlb (bf16), y==1 -> xr (f32) ----------------
// Normalization of previous layer fused into the LDS staging load.
__global__ __launch_bounds__(256) void gemm_kernel(const float* __restrict__ hin,
                                                   const float* __restrict__ Wl,
                                                   const float* __restrict__ Wr,
                                                   unsigned int* __restrict__ xlb,
                                                   float* __restrict__ xr,
                                                   const float* __restrict__ scale,
                                                   const float* __restrict__ shift,
                                                   int donorm) {
    __shared__ float Hsh[64][132];
    const float* __restrict__ W = blockIdx.y ? Wr : Wl;
    int row0 = blockIdx.x * 64;
    int tid = threadIdx.x;
    for (int i = tid; i < 64 * 32; i += 256) {
        int r = i >> 5, c4 = i & 31;
        int gr = row0 + r;
        float4 v = make_float4(0.f, 0.f, 0.f, 0.f);
        if (gr < N_NODES) v = ((const float4*)(hin + (size_t)gr * HID))[c4];
        if (donorm) {
            float4 sc = ((const float4*)scale)[c4];
            float4 sh = ((const float4*)shift)[c4];
            v.x = v.x * sc.x + sh.x; v.y = v.y * sc.y + sh.y;
            v.z = v.z * sc.z + sh.z; v.w = v.w * sc.w + sh.w;
        }
        *(float4*)(&Hsh[r][c4 * 4]) = v;
    }
    __syncthreads();
    int cg = tid & 15;   // col group: cols cg*8 .. cg*8+7
    int rg = tid >> 4;   // row group: rows rg*4 .. rg*4+3
    int c0 = cg * 8;
    float4 acc[4][2];
#pragma unroll
    for (int r = 0; r < 4; r++) {
        acc[r][0] = make_float4(0.f, 0.f, 0.f, 0.f);
        acc[r][1] = make_float4(0.f, 0.f, 0.f, 0.f);
    }
#pragma unroll 8
    for (int k4 = 0; k4 < 32; k4++) {
        float4 h[4];
#pragma unroll
        for (int r = 0; r < 4; r++) h[r] = *(const float4*)(&Hsh[rg * 4 + r][k4 * 4]);
#pragma unroll
        for (int kk = 0; kk < 4; kk++) {
            int k = k4 * 4 + kk;
            float4 w0 = *(const float4*)(W + (size_t)k * HID + c0);
            float4 w1 = *(const float4*)(W + (size_t)k * HID + c0 + 4);
#pragma unroll
            for (int r = 0; r < 4; r++) {
                float hv = ((const float*)&h[r])[kk];
                acc[r][0].x += hv * w0.x; acc[r][0].y += hv * w0.y;
                acc[r][0].z += hv * w0.z; acc[r][0].w += hv * w0.w;
                acc[r][1].x += hv * w1.x; acc[r][1].y += hv * w1.y;
                acc[r][1].z += hv * w1.z; acc[r][1].w += hv * w1.w;
            }
        }
    }
    if (blockIdx.y == 0) {
#pragma unroll
        for (int r = 0; r < 4; r++) {
            int grr = row0 + rg * 4 + r;
            if (grr < N_NODES) {
                uint4 p;
                p.x = packbf2(acc[r][0].x, acc[r][0].y);
                p.y = packbf2(acc[r][0].z, acc[r][0].w);
                p.z = packbf2(acc[r][1].x, acc[r][1].y);
                p.w = packbf2(acc[r][1].z, acc[r][1].w);
                *(uint4*)(xlb + (size_t)grr * 64 + cg * 4) = p;
            }
        }
    } else {
#pragma unroll
        for (int r = 0; r < 4; r++) {
            int grr = row0 + rg * 4 + r;
            if (grr < N_NODES) {
                *(float4*)(xr + (size_t)grr * HID + c0) = acc[r][0];
                *(float4*)(xr + (size_t)grr * HID + c0 + 4) = acc[r][1];
            }
        }
    }
}

// ---------------- Edge aggregation (unchanged from round 4) ----------------
__global__ __launch_bounds__(256) void aggregate_kernel(
    const unsigned int* __restrict__ xlb, const float* __restrict__ xr,
    const float* __restrict__ att, const float* __restrict__ bias,
    const int* __restrict__ rowptr, const int* __restrict__ csr_src,
    float* __restrict__ hout) {
    int node = blockIdx.x * 8 + (threadIdx.x >> 5);
    if (node >= N_NODES) return;
    int hl = threadIdx.x & 31;   // lane within half-wave
    int c0 = hl * 4;             // 4 columns per lane
    const float4 a4 = *(const float4*)(att + c0);
    const float4 r4 = *(const float4*)(xr + (size_t)node * HID + c0);
    int beg = rowptr[node], end = rowptr[node + 1];
    float m = -INFINITY, s = 0.f;
    float4 acc = make_float4(0.f, 0.f, 0.f, 0.f);
    for (int base = beg; base < end; base += 8) {
        int nn = end - base;
        if (nn > 8) nn = 8;
        int idx8 = csr_src[min(base + (hl & 7), end - 1)];
        uint2 v[8];
        float p[8];
#pragma unroll
        for (int j = 0; j < 8; j++) {
            int sj = __shfl(idx8, j, 32);
            v[j] = *(const uint2*)(xlb + (size_t)sj * 64 + hl * 2);
            float v0 = __uint_as_float(v[j].x << 16);
            float v1 = __uint_as_float(v[j].x & 0xffff0000u);
            float v2 = __uint_as_float(v[j].y << 16);
            float v3 = __uint_as_float(v[j].y & 0xffff0000u);
            float s0 = v0 + r4.x, s1 = v1 + r4.y, s2 = v2 + r4.z, s3 = v3 + r4.w;
            p[j] = fmaxf(s0, NEG * s0) * a4.x + fmaxf(s1, NEG * s1) * a4.y +
                   fmaxf(s2, NEG * s2) * a4.z + fmaxf(s3, NEG * s3) * a4.w;
        }
#pragma unroll
        for (int off = 1; off <= 16; off <<= 1) {
#pragma unroll
            for (int j = 0; j < 8; j++) p[j] += __shfl_xor(p[j], off, 32);
        }
#pragma unroll
        for (int j = 0; j < 8; j++)
            if (j >= nn) p[j] = -INFINITY;
        float mc = fmaxf(fmaxf(fmaxf(p[0], p[1]), fmaxf(p[2], p[3])),
                         fmaxf(fmaxf(p[4], p[5]), fmaxf(p[6], p[7])));
        float mnew = fmaxf(m, mc);
        float scale = __expf(m - mnew);  // first chunk: exp(-inf)=0
        s *= scale;
        acc.x *= scale; acc.y *= scale; acc.z *= scale; acc.w *= scale;
        m = mnew;
#pragma unroll
        for (int j = 0; j < 8; j++) {
            float w = __expf(p[j] - mnew);  // masked j: exp(-inf)=0
            s += w;
            float v0 = __uint_as_float(v[j].x << 16);
            float v1 = __uint_as_float(v[j].x & 0xffff0000u);
            float v2 = __uint_as_float(v[j].y << 16);
            float v3 = __uint_as_float(v[j].y & 0xffff0000u);
            acc.x += w * v0; acc.y += w * v1; acc.z += w * v2; acc.w += w * v3;
        }
    }
    float inv = 1.f / s;
    const float4 b4 = *(const float4*)(bias + c0);
    float4 o;
    o.x = acc.x * inv + b4.x; o.y = acc.y * inv + b4.y;
    o.z = acc.z * inv + b4.z; o.w = acc.w * inv + b4.w;
    *(float4*)(hout + (size_t)node * HID + c0) = o;
}

// ---------------- BatchNorm stats ----------------
__global__ __launch_bounds__(256) void bn_reduce_kernel(const float* __restrict__ h,
                                                        float* __restrict__ part) {
    int tid = threadIdx.x;
    int c = tid & 127, half = tid >> 7;
    float s = 0.f, q = 0.f;
    for (int r = blockIdx.x * 2 + half; r < N_NODES; r += RB * 2) {
        float v = h[(size_t)r * HID + c];
        s += v; q += v * v;
    }
    __shared__ float shs[256], shq[256];
    shs[tid] = s; shq[tid] = q;
    __syncthreads();
    if (half == 0) {
        part[blockIdx.x * 256 + c] = s + shs[tid + 128];
        part[blockIdx.x * 256 + 128 + c] = q + shq[tid + 128];
    }
}

__global__ void bn_finalize_kernel(const float* __restrict__ part,
                                   const float* __restrict__ gamma,
                                   const float* __restrict__ beta,
                                   float* __restrict__ scale, float* __restrict__ shift) {
    int c = threadIdx.x;  // 128 threads
    float s = 0.f, q = 0.f;
    for (int b = 0; b < RB; b++) {
        s += part[b * 256 + c];
        q += part[b * 256 + 128 + c];
    }
    float m = s / (float)N_NODES;
    float v = q / (float)N_NODES - m * m;
    if (v < 0.f) v = 0.f;
    float rs = rsqrtf(v + EPS);
    float sc = rs * gamma[c];
    scale[c] = sc;
    shift[c] = beta[c] - m * sc;
}

// Residual accumulate of normalized h (norm applied on the fly).
__global__ __launch_bounds__(256) void accb_kernel(const float* __restrict__ h,
                                                   const float* __restrict__ scale,
                                                   const float* __restrict__ shift,
                                                   float* __restrict__ acc, int first) {
    int idx = blockIdx.x * 256 + threadIdx.x;
    if (idx >= N_NODES * HID) return;
    int c = idx & 127;
    float v = h[idx] * scale[c] + shift[c];
    float a = 0.2f * v;  // resw = 1/(N_LAYERS+1)
    acc[idx] = first ? a : acc[idx] + a;
}

// ---------------- Decode: per-pair dot product ----------------
__global__ __launch_bounds__(256) void predict_kernel(const float* __restrict__ acc,
                                                      const int* __restrict__ eli,
                                                      float* __restrict__ out) {
    int p = blockIdx.x * 4 + (threadIdx.x >> 6);
    if (p >= 8192) return;
    int lane = threadIdx.x & 63;
    int i = eli[p], j = eli[8192 + p];
    const float2 va = *(const float2*)(acc + (size_t)i * HID + lane * 2);
    const float2 vb = *(const float2*)(acc + (size_t)j * HID + lane * 2);
    float t = va.x * vb.x + va.y * vb.y;
#pragma unroll
    for (int off = 32; off; off >>= 1) t += __shfl_xor(t, off, 64);
    if (lane == 0) out[p] = t;
}

extern "C" void kernel_launch(void* const* d_in, const int* in_sizes, int n_in,
                              void* d_out, int out_size, void* d_ws, size_t ws_size,
                              hipStream_t stream) {
    const float* x = (const float*)d_in[0];
    const int* ei = (const int*)d_in[1];
    const int* eli = (const int*)d_in[2];
    const float* Wl = (const float*)d_in[3];
    const float* Wr = (const float*)d_in[4];
    const float* att = (const float*)d_in[5];
    const float* bias = (const float*)d_in[6];
    const float* gamma = (const float*)d_in[7];
    const float* beta = (const float*)d_in[8];
    float* out = (float*)d_out;

    char* ws = (char*)d_ws;
    size_t off = 0;
    float* hbuf = (float*)(ws + off); off += (size_t)N_NODES * HID * 4;
    float* xr   = (float*)(ws + off); off += (size_t)N_NODES * HID * 4;
    float* accb = (float*)(ws + off); off += (size_t)N_NODES * HID * 4;
    unsigned int* xlb = (unsigned int*)(ws + off); off += (size_t)N_NODES * HID * 2;  // bf16
    int* rowptr = (int*)(ws + off);   off += ((size_t)(N_NODES + 1) * 4 + 31) & ~31ul;
    int* csr_src = (int*)(ws + off);  off += (size_t)(ET + 8) * 4;
    int* gcnt  = (int*)(ws + off);    off += (size_t)NBUCK * 4;
    int* bcur  = (int*)(ws + off);    off += (size_t)NBUCK * 4;
    int* bbase = (int*)(ws + off);    off += (size_t)(NBUCK + 1) * 4;
    float* part = (float*)(ws + off); off += (size_t)RB * 256 * 4;
    float* scale = (float*)(ws + off); off += 128 * 4;
    float* shift = (float*)(ws + off); off += 128 * 4;
    // pairs buffer aliases accb: only live during CSR build, before accb's first write
    unsigned int* pairs = (unsigned int*)accb;

    // CSR build (dst-sorted), bucketed counting sort; topology fixed across layers
    int nablk = (ET + BCHUNK - 1) / BCHUNK;
    bucket_zero_kernel<<<(NBUCK + 255) / 256, 256, 0, stream>>>(gcnt);
    bucket_hist_kernel<<<nablk, 256, 0, stream>>>(ei, gcnt);
    bucket_scan_kernel<<<1, 1024, 0, stream>>>(gcnt, bbase, bcur, rowptr);
    bucket_scatter_kernel<<<nablk, 256, 0, stream>>>(ei, bcur, pairs);
    bucket_sort_kernel<<<NBUCK, 256, 0, stream>>>(pairs, bbase, rowptr, csr_src);

    for (int l = 0; l < N_LAYERS; l++) {
        const float* hin = (l == 0) ? x : hbuf;
        gemm_kernel<<<dim3((N_NODES + 63) / 64, 2), 256, 0, stream>>>(
            hin, Wl + (size_t)l * HID * HID, Wr + (size_t)l * HID * HID, xlb, xr,
            scale, shift, l == 0 ? 0 : 1);
        aggregate_kernel<<<(N_NODES + 7) / 8, 256, 0, stream>>>(
            xlb, xr, att + l * HID, bias + l * HID, rowptr, csr_src, hbuf);
        bn_reduce_kernel<<<RB, 256, 0, stream>>>(hbuf, part);
        bn_finalize_kernel<<<1, 128, 0, stream>>>(part, gamma + l * HID, beta + l * HID,
                                                  scale, shift);
        accb_kernel<<<(N_NODES * HID + 255) / 256, 256, 0, stream>>>(
            hbuf, scale, shift, accb, l == 0 ? 1 : 0);
    }
    predict_kernel<<<8192 / 4, 256, 0, stream>>>(accb, eli, out);
}

// Round 6
// 709.891 us; speedup vs baseline: 2.7358x; 1.2947x over previous
//
#include <hip/hip_runtime.h>
#include <hip/hip_bf16.h>

#define N_NODES 50000
#define N_EDGES 1600000
#define ET (N_EDGES + N_NODES)
#define HID 128
#define N_LAYERS 4
#define EPS 1e-5f
#define NEG 0.2f
#define RB 256     // bn reduce blocks
#define NBUCK 782  // ceil(N_NODES/64)
#define BCHUNK 8192

typedef __attribute__((ext_vector_type(8))) short s16x8;
typedef __attribute__((ext_vector_type(8))) __bf16 bfx8;
typedef __attribute__((ext_vector_type(4))) float fx4;

__device__ __forceinline__ unsigned int packbf2(float a, float b) {
    unsigned int ua = __float_as_uint(a);
    ua = (ua + 0x7fffu + ((ua >> 16) & 1u)) >> 16;
    unsigned int ub = __float_as_uint(b);
    ub = (ub + 0x7fffu + ((ub >> 16) & 1u)) & 0xffff0000u;
    return (ua & 0xffffu) | ub;
}
__device__ __forceinline__ unsigned short bf16r(float a) {
    unsigned int ua = __float_as_uint(a);
    return (unsigned short)((ua + 0x7fffu + ((ua >> 16) & 1u)) >> 16);
}

// ---------------- CSR build: two-level bucketed counting sort ----------------
__global__ void bucket_zero_kernel(int* __restrict__ gcnt) {
    int i = blockIdx.x * 256 + threadIdx.x;
    if (i < NBUCK) gcnt[i] = 0;
}

__global__ __launch_bounds__(256) void bucket_hist_kernel(const int* __restrict__ ei,
                                                          int* __restrict__ gcnt) {
    __shared__ int h[NBUCK];
    for (int i = threadIdx.x; i < NBUCK; i += 256) h[i] = 0;
    __syncthreads();
    int base = blockIdx.x * BCHUNK;
    int lim = min(base + BCHUNK, ET);
    for (int i = base + threadIdx.x; i < lim; i += 256) {
        int dst = (i < N_EDGES) ? ei[N_EDGES + i] : i - N_EDGES;
        atomicAdd(&h[dst >> 6], 1);
    }
    __syncthreads();
    for (int i = threadIdx.x; i < NBUCK; i += 256)
        if (h[i]) atomicAdd(&gcnt[i], h[i]);
}

__global__ void bucket_scan_kernel(const int* __restrict__ gcnt, int* __restrict__ bbase,
                                   int* __restrict__ bcur, int* __restrict__ rowptr) {
    __shared__ int sh[1024];
    int tid = threadIdx.x;
    int v = (tid < NBUCK) ? gcnt[tid] : 0;
    sh[tid] = v;
    __syncthreads();
    for (int off = 1; off < 1024; off <<= 1) {
        int t = (tid >= off) ? sh[tid - off] : 0;
        __syncthreads();
        sh[tid] += t;
        __syncthreads();
    }
    if (tid < NBUCK) {
        int ex = sh[tid] - v;
        bbase[tid] = ex;
        bcur[tid] = ex;
    }
    if (tid == NBUCK - 1) bbase[NBUCK] = sh[tid];
    if (tid == 0) rowptr[N_NODES] = ET;
}

__global__ __launch_bounds__(256) void bucket_scatter_kernel(const int* __restrict__ ei,
                                                             int* __restrict__ bcur,
                                                             unsigned int* __restrict__ pairs) {
    __shared__ int h[NBUCK];
    __shared__ int rbase[NBUCK];
    for (int i = threadIdx.x; i < NBUCK; i += 256) h[i] = 0;
    __syncthreads();
    int base = blockIdx.x * BCHUNK;
    int lim = min(base + BCHUNK, ET);
    for (int i = base + threadIdx.x; i < lim; i += 256) {
        int dst = (i < N_EDGES) ? ei[N_EDGES + i] : i - N_EDGES;
        atomicAdd(&h[dst >> 6], 1);
    }
    __syncthreads();
    for (int i = threadIdx.x; i < NBUCK; i += 256) {
        rbase[i] = h[i] ? atomicAdd(&bcur[i], h[i]) : 0;
        h[i] = 0;
    }
    __syncthreads();
    for (int i = base + threadIdx.x; i < lim; i += 256) {
        int src, dst;
        if (i < N_EDGES) { src = ei[i]; dst = ei[N_EDGES + i]; }
        else { src = dst = i - N_EDGES; }
        int b = dst >> 6;
        int pos = rbase[b] + atomicAdd(&h[b], 1);
        pairs[pos] = (unsigned int)src | ((unsigned int)(dst & 63) << 16);
    }
}

__global__ __launch_bounds__(256) void bucket_sort_kernel(const unsigned int* __restrict__ pairs,
                                                          const int* __restrict__ bbase,
                                                          int* __restrict__ rowptr,
                                                          int* __restrict__ csr_src) {
    __shared__ int h[64], ex[64], cur[64];
    int b = blockIdx.x;
    int tid = threadIdx.x;
    if (tid < 64) h[tid] = 0;
    __syncthreads();
    int bs = bbase[b], be = bbase[b + 1];
    for (int i = bs + tid; i < be; i += 256) atomicAdd(&h[pairs[i] >> 16], 1);
    __syncthreads();
    if (tid == 0) {
        int run = 0;
        for (int k = 0; k < 64; k++) { ex[k] = run; cur[k] = run; run += h[k]; }
    }
    __syncthreads();
    int n0 = b * 64;
    if (tid < 64 && n0 + tid < N_NODES) rowptr[n0 + tid] = bs + ex[tid];
    for (int i = bs + tid; i < be; i += 256) {
        unsigned int u = pairs[i];
        int ln = u >> 16;
        int pos = bs + atomicAdd(&cur[ln], 1);
        csr_src[pos] = (int)(u & 0xffffu);
    }
}

// ---------------- Weight convert: W[k][c] f32 -> Wt[c][k] bf16, all 8 mats ----------------
__global__ __launch_bounds__(256) void wconv_kernel(const float* __restrict__ Wl,
                                                    const float* __restrict__ Wr,
                                                    unsigned short* __restrict__ wt) {
    int m = blockIdx.x;  // 0..7: layer = m>>1, mat = m&1
    const float* __restrict__ W = ((m & 1) ? Wr : Wl) + (size_t)(m >> 1) * HID * HID;
    unsigned short* __restrict__ o = wt + (size_t)m * HID * HID;
    for (int i = threadIdx.x; i < HID * HID; i += 256) {
        int k = i >> 7, c = i & 127;
        o[c * HID + k] = bf16r(W[i]);
    }
}

// ---------------- MFMA GEMM: y==0 -> xlb (bf16), y==1 -> xr (f32) ----------------
// 128 rows x 128 cols per block, 4 waves (each 32 rows x 128 cols).
// A (h, normalized on the fly, bf16) and Wt both in LDS, XOR-swizzled 16B chunks.
__global__ __launch_bounds__(256) void gemm_mfma_kernel(
    const float* __restrict__ hin, const unsigned short* __restrict__ wt_layer,
    unsigned int* __restrict__ xlb, float* __restrict__ xr,
    const float* __restrict__ scale, const float* __restrict__ shift, int donorm) {
    __shared__ unsigned int Ash[128 * 64];  // 32KB, row stride 64 uints
    __shared__ unsigned int Wsh[128 * 64];  // 32KB, col stride 64 uints
    int row0 = blockIdx.x * 128;
    int tid = threadIdx.x;
    // stage A: i = row*16 + chunk; chunk = 16B = 8 bf16 = cols ch*8..+7
    for (int i = tid; i < 2048; i += 256) {
        int r = i >> 4, ch = i & 15;
        int gr = row0 + r;
        uint4 pk = make_uint4(0u, 0u, 0u, 0u);
        if (gr < N_NODES) {
            const float4* src = (const float4*)(hin + (size_t)gr * HID + ch * 8);
            float4 va = src[0], vb = src[1];
            if (donorm) {
                const float4* s4 = (const float4*)(scale + ch * 8);
                const float4* t4 = (const float4*)(shift + ch * 8);
                float4 s0 = s4[0], s1 = s4[1], t0 = t4[0], t1 = t4[1];
                va.x = va.x * s0.x + t0.x; va.y = va.y * s0.y + t0.y;
                va.z = va.z * s0.z + t0.z; va.w = va.w * s0.w + t0.w;
                vb.x = vb.x * s1.x + t1.x; vb.y = vb.y * s1.y + t1.y;
                vb.z = vb.z * s1.z + t1.z; vb.w = vb.w * s1.w + t1.w;
            }
            pk.x = packbf2(va.x, va.y); pk.y = packbf2(va.z, va.w);
            pk.z = packbf2(vb.x, vb.y); pk.w = packbf2(vb.z, vb.w);
        }
        *(uint4*)(&Ash[r * 64 + ((ch ^ (r & 7)) << 2)]) = pk;
    }
    // stage Wt (this matrix, selected by blockIdx.y): already bf16 [col][k]
    {
        const uint4* wm4 = (const uint4*)(wt_layer + (size_t)blockIdx.y * HID * HID);
        for (int i = tid; i < 2048; i += 256) {
            int c = i >> 4, ch = i & 15;
            uint4 v = wm4[i];
            *(uint4*)(&Wsh[c * 64 + ((ch ^ (c & 7)) << 2)]) = v;
        }
    }
    __syncthreads();

    int l = tid & 63, w = tid >> 6;
    int lr = l & 15, lk = l >> 4;  // fragment row/col sel, k-chunk sel
    fx4 acc0[8], acc1[8];
#pragma unroll
    for (int ct = 0; ct < 8; ct++) {
        acc0[ct] = (fx4){0.f, 0.f, 0.f, 0.f};
        acc1[ct] = (fx4){0.f, 0.f, 0.f, 0.f};
    }
#pragma unroll
    for (int kt = 0; kt < 4; kt++) {
        int ch = kt * 4 + lk;
        int r0 = w * 32 + lr, r1 = r0 + 16;
        bfx8 a0 = __builtin_bit_cast(bfx8, *(const s16x8*)(&Ash[r0 * 64 + ((ch ^ (r0 & 7)) << 2)]));
        bfx8 a1 = __builtin_bit_cast(bfx8, *(const s16x8*)(&Ash[r1 * 64 + ((ch ^ (r1 & 7)) << 2)]));
#pragma unroll
        for (int ct = 0; ct < 8; ct++) {
            int c = ct * 16 + lr;
            bfx8 b = __builtin_bit_cast(bfx8, *(const s16x8*)(&Wsh[c * 64 + ((ch ^ (c & 7)) << 2)]));
            acc0[ct] = __builtin_amdgcn_mfma_f32_16x16x32_bf16(a0, b, acc0[ct], 0, 0, 0);
            acc1[ct] = __builtin_amdgcn_mfma_f32_16x16x32_bf16(a1, b, acc1[ct], 0, 0, 0);
        }
    }
    // C/D: col = lane&15, row = (lane>>4)*4 + reg   [m89-verified]
    int rbase = row0 + w * 32 + lk * 4;
    if (blockIdx.y == 0) {
        unsigned short* o = (unsigned short*)xlb;
#pragma unroll
        for (int ct = 0; ct < 8; ct++) {
            int gc = ct * 16 + lr;
#pragma unroll
            for (int j = 0; j < 4; j++) {
                int g0 = rbase + j;
                if (g0 < N_NODES) o[(size_t)g0 * HID + gc] = bf16r(acc0[ct][j]);
                int g1 = g0 + 16;
                if (g1 < N_NODES) o[(size_t)g1 * HID + gc] = bf16r(acc1[ct][j]);
            }
        }
    } else {
#pragma unroll
        for (int ct = 0; ct < 8; ct++) {
            int gc = ct * 16 + lr;
#pragma unroll
            for (int j = 0; j < 4; j++) {
                int g0 = rbase + j;
                if (g0 < N_NODES) xr[(size_t)g0 * HID + gc] = acc0[ct][j];
                int g1 = g0 + 16;
                if (g1 < N_NODES) xr[(size_t)g1 * HID + gc] = acc1[ct][j];
            }
        }
    }
}

// ---------------- Edge aggregation (unchanged) ----------------
__global__ __launch_bounds__(256) void aggregate_kernel(
    const unsigned int* __restrict__ xlb, const float* __restrict__ xr,
    const float* __restrict__ att, const float* __restrict__ bias,
    const int* __restrict__ rowptr, const int* __restrict__ csr_src,
    float* __restrict__ hout) {
    int node = blockIdx.x * 8 + (threadIdx.x >> 5);
    if (node >= N_NODES) return;
    int hl = threadIdx.x & 31;
    int c0 = hl * 4;
    const float4 a4 = *(const float4*)(att + c0);
    const float4 r4 = *(const float4*)(xr + (size_t)node * HID + c0);
    int beg = rowptr[node], end = rowptr[node + 1];
    float m = -INFINITY, s = 0.f;
    float4 acc = make_float4(0.f, 0.f, 0.f, 0.f);
    for (int base = beg; base < end; base += 8) {
        int nn = end - base;
        if (nn > 8) nn = 8;
        int idx8 = csr_src[min(base + (hl & 7), end - 1)];
        uint2 v[8];
        float p[8];
#pragma unroll
        for (int j = 0; j < 8; j++) {
            int sj = __shfl(idx8, j, 32);
            v[j] = *(const uint2*)(xlb + (size_t)sj * 64 + hl * 2);
            float v0 = __uint_as_float(v[j].x << 16);
            float v1 = __uint_as_float(v[j].x & 0xffff0000u);
            float v2 = __uint_as_float(v[j].y << 16);
            float v3 = __uint_as_float(v[j].y & 0xffff0000u);
            float s0 = v0 + r4.x, s1 = v1 + r4.y, s2 = v2 + r4.z, s3 = v3 + r4.w;
            p[j] = fmaxf(s0, NEG * s0) * a4.x + fmaxf(s1, NEG * s1) * a4.y +
                   fmaxf(s2, NEG * s2) * a4.z + fmaxf(s3, NEG * s3) * a4.w;
        }
#pragma unroll
        for (int off = 1; off <= 16; off <<= 1) {
#pragma unroll
            for (int j = 0; j < 8; j++) p[j] += __shfl_xor(p[j], off, 32);
        }
#pragma unroll
        for (int j = 0; j < 8; j++)
            if (j >= nn) p[j] = -INFINITY;
        float mc = fmaxf(fmaxf(fmaxf(p[0], p[1]), fmaxf(p[2], p[3])),
                         fmaxf(fmaxf(p[4], p[5]), fmaxf(p[6], p[7])));
        float mnew = fmaxf(m, mc);
        float scale = __expf(m - mnew);
        s *= scale;
        acc.x *= scale; acc.y *= scale; acc.z *= scale; acc.w *= scale;
        m = mnew;
#pragma unroll
        for (int j = 0; j < 8; j++) {
            float w = __expf(p[j] - mnew);
            s += w;
            float v0 = __uint_as_float(v[j].x << 16);
            float v1 = __uint_as_float(v[j].x & 0xffff0000u);
            float v2 = __uint_as_float(v[j].y << 16);
            float v3 = __uint_as_float(v[j].y & 0xffff0000u);
            acc.x += w * v0; acc.y += w * v1; acc.z += w * v2; acc.w += w * v3;
        }
    }
    float inv = 1.f / s;
    const float4 b4 = *(const float4*)(bias + c0);
    float4 o;
    o.x = acc.x * inv + b4.x; o.y = acc.y * inv + b4.y;
    o.z = acc.z * inv + b4.z; o.w = acc.w * inv + b4.w;
    *(float4*)(hout + (size_t)node * HID + c0) = o;
}

// ---------------- BatchNorm stats ----------------
__global__ __launch_bounds__(256) void bn_reduce_kernel(const float* __restrict__ h,
                                                        float* __restrict__ part) {
    int tid = threadIdx.x;
    int c = tid & 127, half = tid >> 7;
    float s = 0.f, q = 0.f;
    for (int r = blockIdx.x * 2 + half; r < N_NODES; r += RB * 2) {
        float v = h[(size_t)r * HID + c];
        s += v; q += v * v;
    }
    __shared__ float shs[256], shq[256];
    shs[tid] = s; shq[tid] = q;
    __syncthreads();
    if (half == 0) {
        part[blockIdx.x * 256 + c] = s + shs[tid + 128];
        part[blockIdx.x * 256 + 128 + c] = q + shq[tid + 128];
    }
}

__global__ void bn_finalize_kernel(const float* __restrict__ part,
                                   const float* __restrict__ gamma,
                                   const float* __restrict__ beta,
                                   float* __restrict__ scale, float* __restrict__ shift) {
    int c = threadIdx.x;  // 128 threads
    float s = 0.f, q = 0.f;
    for (int b = 0; b < RB; b++) {
        s += part[b * 256 + c];
        q += part[b * 256 + 128 + c];
    }
    float m = s / (float)N_NODES;
    float v = q / (float)N_NODES - m * m;
    if (v < 0.f) v = 0.f;
    float rs = rsqrtf(v + EPS);
    float sc = rs * gamma[c];
    scale[c] = sc;
    shift[c] = beta[c] - m * sc;
}

// Residual accumulate of normalized h (norm applied on the fly).
__global__ __launch_bounds__(256) void accb_kernel(const float* __restrict__ h,
                                                   const float* __restrict__ scale,
                                                   const float* __restrict__ shift,
                                                   float* __restrict__ acc, int first) {
    int idx = blockIdx.x * 256 + threadIdx.x;
    if (idx >= N_NODES * HID) return;
    int c = idx & 127;
    float v = h[idx] * scale[c] + shift[c];
    float a = 0.2f * v;  // resw = 1/(N_LAYERS+1)
    acc[idx] = first ? a : acc[idx] + a;
}

// ---------------- Decode: per-pair dot product ----------------
__global__ __launch_bounds__(256) void predict_kernel(const float* __restrict__ acc,
                                                      const int* __restrict__ eli,
                                                      float* __restrict__ out) {
    int p = blockIdx.x * 4 + (threadIdx.x >> 6);
    if (p >= 8192) return;
    int lane = threadIdx.x & 63;
    int i = eli[p], j = eli[8192 + p];
    const float2 va = *(const float2*)(acc + (size_t)i * HID + lane * 2);
    const float2 vb = *(const float2*)(acc + (size_t)j * HID + lane * 2);
    float t = va.x * vb.x + va.y * vb.y;
#pragma unroll
    for (int off = 32; off; off >>= 1) t += __shfl_xor(t, off, 64);
    if (lane == 0) out[p] = t;
}

extern "C" void kernel_launch(void* const* d_in, const int* in_sizes, int n_in,
                              void* d_out, int out_size, void* d_ws, size_t ws_size,
                              hipStream_t stream) {
    const float* x = (const float*)d_in[0];
    const int* ei = (const int*)d_in[1];
    const int* eli = (const int*)d_in[2];
    const float* Wl = (const float*)d_in[3];
    const float* Wr = (const float*)d_in[4];
    const float* att = (const float*)d_in[5];
    const float* bias = (const float*)d_in[6];
    const float* gamma = (const float*)d_in[7];
    const float* beta = (const float*)d_in[8];
    float* out = (float*)d_out;

    char* ws = (char*)d_ws;
    size_t off = 0;
    float* hbuf = (float*)(ws + off); off += (size_t)N_NODES * HID * 4;
    float* xr   = (float*)(ws + off); off += (size_t)N_NODES * HID * 4;
    float* accb = (float*)(ws + off); off += (size_t)N_NODES * HID * 4;
    unsigned int* xlb = (unsigned int*)(ws + off); off += (size_t)N_NODES * HID * 2;  // bf16
    int* rowptr = (int*)(ws + off);   off += ((size_t)(N_NODES + 1) * 4 + 31) & ~31ul;
    int* csr_src = (int*)(ws + off);  off += (size_t)(ET + 8) * 4;
    int* gcnt  = (int*)(ws + off);    off += (size_t)NBUCK * 4;
    int* bcur  = (int*)(ws + off);    off += (size_t)NBUCK * 4;
    int* bbase = (int*)(ws + off);    off += (size_t)(NBUCK + 1) * 4;
    float* part = (float*)(ws + off); off += (size_t)RB * 256 * 4;
    float* scale = (float*)(ws + off); off += 128 * 4;
    float* shift = (float*)(ws + off); off += 128 * 4;
    unsigned short* wt = (unsigned short*)(ws + off); off += (size_t)8 * HID * HID * 2;
    // pairs buffer aliases accb: only live during CSR build, before accb's first write
    unsigned int* pairs = (unsigned int*)accb;

    // One-time: weights -> bf16 transposed [layer][mat][col][k]
    wconv_kernel<<<8, 256, 0, stream>>>(Wl, Wr, wt);

    // CSR build (dst-sorted), bucketed counting sort; topology fixed across layers
    int nablk = (ET + BCHUNK - 1) / BCHUNK;
    bucket_zero_kernel<<<(NBUCK + 255) / 256, 256, 0, stream>>>(gcnt);
    bucket_hist_kernel<<<nablk, 256, 0, stream>>>(ei, gcnt);
    bucket_scan_kernel<<<1, 1024, 0, stream>>>(gcnt, bbase, bcur, rowptr);
    bucket_scatter_kernel<<<nablk, 256, 0, stream>>>(ei, bcur, pairs);
    bucket_sort_kernel<<<NBUCK, 256, 0, stream>>>(pairs, bbase, rowptr, csr_src);

    for (int l = 0; l < N_LAYERS; l++) {
        const float* hin = (l == 0) ? x : hbuf;
        gemm_mfma_kernel<<<dim3((N_NODES + 127) / 128, 2), 256, 0, stream>>>(
            hin, wt + (size_t)l * 2 * HID * HID, xlb, xr, scale, shift, l == 0 ? 0 : 1);
        aggregate_kernel<<<(N_NODES + 7) / 8, 256, 0, stream>>>(
            xlb, xr, att + l * HID, bias + l * HID, rowptr, csr_src, hbuf);
        bn_reduce_kernel<<<RB, 256, 0, stream>>>(hbuf, part);
        bn_finalize_kernel<<<1, 128, 0, stream>>>(part, gamma + l * HID, beta + l * HID,
                                                  scale, shift);
        accb_kernel<<<(N_NODES * HID + 255) / 256, 256, 0, stream>>>(
            hbuf, scale, shift, accb, l == 0 ? 1 : 0);
    }
    predict_kernel<<<8192 / 4, 256, 0, stream>>>(accb, eli, out);
}

// Round 7
// 696.458 us; speedup vs baseline: 2.7886x; 1.0193x over previous
//
#include <hip/hip_runtime.h>
#include <hip/hip_bf16.h>

#define N_NODES 50000
#define N_EDGES 1600000
#define ET (N_EDGES + N_NODES)
#define HID 128
#define N_LAYERS 4
#define EPS 1e-5f
#define NEG 0.2f
#define RB 256     // bn reduce blocks
#define NBUCK 782  // ceil(N_NODES/64)
#define BCHUNK 8192
#define LOG2E 1.44269504088896f

typedef __attribute__((ext_vector_type(8))) short s16x8;
typedef __attribute__((ext_vector_type(8))) __bf16 bfx8;
typedef __attribute__((ext_vector_type(4))) float fx4;

__device__ __forceinline__ unsigned int packbf2(float a, float b) {
    unsigned int ua = __float_as_uint(a);
    ua = (ua + 0x7fffu + ((ua >> 16) & 1u)) >> 16;
    unsigned int ub = __float_as_uint(b);
    ub = (ub + 0x7fffu + ((ub >> 16) & 1u)) & 0xffff0000u;
    return (ua & 0xffffu) | ub;
}
__device__ __forceinline__ unsigned short bf16r(float a) {
    unsigned int ua = __float_as_uint(a);
    return (unsigned short)((ua + 0x7fffu + ((ua >> 16) & 1u)) >> 16);
}

// ---------------- CSR build: two-level bucketed counting sort ----------------
__global__ void bucket_zero_kernel(int* __restrict__ gcnt) {
    int i = blockIdx.x * 256 + threadIdx.x;
    if (i < NBUCK) gcnt[i] = 0;
}

__global__ __launch_bounds__(256) void bucket_hist_kernel(const int* __restrict__ ei,
                                                          int* __restrict__ gcnt) {
    __shared__ int h[NBUCK];
    for (int i = threadIdx.x; i < NBUCK; i += 256) h[i] = 0;
    __syncthreads();
    int base = blockIdx.x * BCHUNK;
    int lim = min(base + BCHUNK, ET);
    for (int i = base + threadIdx.x; i < lim; i += 256) {
        int dst = (i < N_EDGES) ? ei[N_EDGES + i] : i - N_EDGES;
        atomicAdd(&h[dst >> 6], 1);
    }
    __syncthreads();
    for (int i = threadIdx.x; i < NBUCK; i += 256)
        if (h[i]) atomicAdd(&gcnt[i], h[i]);
}

__global__ void bucket_scan_kernel(const int* __restrict__ gcnt, int* __restrict__ bbase,
                                   int* __restrict__ bcur, int* __restrict__ rowptr) {
    __shared__ int sh[1024];
    int tid = threadIdx.x;
    int v = (tid < NBUCK) ? gcnt[tid] : 0;
    sh[tid] = v;
    __syncthreads();
    for (int off = 1; off < 1024; off <<= 1) {
        int t = (tid >= off) ? sh[tid - off] : 0;
        __syncthreads();
        sh[tid] += t;
        __syncthreads();
    }
    if (tid < NBUCK) {
        int ex = sh[tid] - v;
        bbase[tid] = ex;
        bcur[tid] = ex;
    }
    if (tid == NBUCK - 1) bbase[NBUCK] = sh[tid];
    if (tid == 0) rowptr[N_NODES] = ET;
}

__global__ __launch_bounds__(256) void bucket_scatter_kernel(const int* __restrict__ ei,
                                                             int* __restrict__ bcur,
                                                             unsigned int* __restrict__ pairs) {
    __shared__ int h[NBUCK];
    __shared__ int rbase[NBUCK];
    for (int i = threadIdx.x; i < NBUCK; i += 256) h[i] = 0;
    __syncthreads();
    int base = blockIdx.x * BCHUNK;
    int lim = min(base + BCHUNK, ET);
    for (int i = base + threadIdx.x; i < lim; i += 256) {
        int dst = (i < N_EDGES) ? ei[N_EDGES + i] : i - N_EDGES;
        atomicAdd(&h[dst >> 6], 1);
    }
    __syncthreads();
    for (int i = threadIdx.x; i < NBUCK; i += 256) {
        rbase[i] = h[i] ? atomicAdd(&bcur[i], h[i]) : 0;
        h[i] = 0;
    }
    __syncthreads();
    for (int i = base + threadIdx.x; i < lim; i += 256) {
        int src, dst;
        if (i < N_EDGES) { src = ei[i]; dst = ei[N_EDGES + i]; }
        else { src = dst = i - N_EDGES; }
        int b = dst >> 6;
        int pos = rbase[b] + atomicAdd(&h[b], 1);
        pairs[pos] = (unsigned int)src | ((unsigned int)(dst & 63) << 16);
    }
}

__global__ __launch_bounds__(256) void bucket_sort_kernel(const unsigned int* __restrict__ pairs,
                                                          const int* __restrict__ bbase,
                                                          int* __restrict__ rowptr,
                                                          int* __restrict__ csr_src) {
    __shared__ int h[64], ex[64], cur[64];
    int b = blockIdx.x;
    int tid = threadIdx.x;
    if (tid < 64) h[tid] = 0;
    __syncthreads();
    int bs = bbase[b], be = bbase[b + 1];
    for (int i = bs + tid; i < be; i += 256) atomicAdd(&h[pairs[i] >> 16], 1);
    __syncthreads();
    if (tid == 0) {
        int run = 0;
        for (int k = 0; k < 64; k++) { ex[k] = run; cur[k] = run; run += h[k]; }
    }
    __syncthreads();
    int n0 = b * 64;
    if (tid < 64 && n0 + tid < N_NODES) rowptr[n0 + tid] = bs + ex[tid];
    for (int i = bs + tid; i < be; i += 256) {
        unsigned int u = pairs[i];
        int ln = u >> 16;
        int pos = bs + atomicAdd(&cur[ln], 1);
        csr_src[pos] = (int)(u & 0xffffu);
    }
}

// ---------------- Weight convert: W[k][c] f32 -> Wt[c][k] bf16, all 8 mats ----------------
__global__ __launch_bounds__(256) void wconv_kernel(const float* __restrict__ Wl,
                                                    const float* __restrict__ Wr,
                                                    unsigned short* __restrict__ wt) {
    int m = blockIdx.x;  // 0..7: layer = m>>1, mat = m&1
    const float* __restrict__ W = ((m & 1) ? Wr : Wl) + (size_t)(m >> 1) * HID * HID;
    unsigned short* __restrict__ o = wt + (size_t)m * HID * HID;
    for (int i = threadIdx.x; i < HID * HID; i += 256) {
        int k = i >> 7, c = i & 127;
        o[c * HID + k] = bf16r(W[i]);
    }
}

// ---------------- MFMA GEMM (swapped operands): y==0 -> xlb, y==1 -> xrb (both bf16) ----
// 128 rows x 128 cols per block, 4 waves. A(h, normalized) + Wt in LDS (swizzled).
// mfma(W_frag, A_frag): D col = node row -> each thread holds 4 consecutive out-cols
// of one node => packed uint2 stores. Residual accumulate fused into A staging.
__global__ __launch_bounds__(256) void gemm_mfma_kernel(
    const float* __restrict__ hin, const unsigned short* __restrict__ wt_layer,
    unsigned int* __restrict__ xlb, unsigned int* __restrict__ xrb,
    const float* __restrict__ scale, const float* __restrict__ shift,
    float* __restrict__ accb, int donorm, int accmode) {  // accmode: 0 none, 1 first, 2 add
    __shared__ unsigned int Ash[128 * 64];  // 32KB
    __shared__ unsigned int Wsh[128 * 64];  // 32KB
    int row0 = blockIdx.x * 128;
    int tid = threadIdx.x;
    for (int i = tid; i < 2048; i += 256) {
        int r = i >> 4, ch = i & 15;
        int gr = row0 + r;
        uint4 pk = make_uint4(0u, 0u, 0u, 0u);
        if (gr < N_NODES) {
            const float4* src = (const float4*)(hin + (size_t)gr * HID + ch * 8);
            float4 va = src[0], vb = src[1];
            if (donorm) {
                const float4* s4 = (const float4*)(scale + ch * 8);
                const float4* t4 = (const float4*)(shift + ch * 8);
                float4 s0 = s4[0], s1 = s4[1], t0 = t4[0], t1 = t4[1];
                va.x = va.x * s0.x + t0.x; va.y = va.y * s0.y + t0.y;
                va.z = va.z * s0.z + t0.z; va.w = va.w * s0.w + t0.w;
                vb.x = vb.x * s1.x + t1.x; vb.y = vb.y * s1.y + t1.y;
                vb.z = vb.z * s1.z + t1.z; vb.w = vb.w * s1.w + t1.w;
            }
            if (accmode && blockIdx.y == 0) {
                float4* ap = (float4*)(accb + (size_t)gr * HID + ch * 8);
                float4 ra, rb;
                if (accmode == 1) {
                    ra = make_float4(0.2f * va.x, 0.2f * va.y, 0.2f * va.z, 0.2f * va.w);
                    rb = make_float4(0.2f * vb.x, 0.2f * vb.y, 0.2f * vb.z, 0.2f * vb.w);
                } else {
                    ra = ap[0]; rb = ap[1];
                    ra.x += 0.2f * va.x; ra.y += 0.2f * va.y; ra.z += 0.2f * va.z; ra.w += 0.2f * va.w;
                    rb.x += 0.2f * vb.x; rb.y += 0.2f * vb.y; rb.z += 0.2f * vb.z; rb.w += 0.2f * vb.w;
                }
                ap[0] = ra; ap[1] = rb;
            }
            pk.x = packbf2(va.x, va.y); pk.y = packbf2(va.z, va.w);
            pk.z = packbf2(vb.x, vb.y); pk.w = packbf2(vb.z, vb.w);
        }
        *(uint4*)(&Ash[r * 64 + ((ch ^ (r & 7)) << 2)]) = pk;
    }
    {
        const uint4* wm4 = (const uint4*)(wt_layer + (size_t)blockIdx.y * HID * HID);
        for (int i = tid; i < 2048; i += 256) {
            int c = i >> 4, ch = i & 15;
            uint4 v = wm4[i];
            *(uint4*)(&Wsh[c * 64 + ((ch ^ (c & 7)) << 2)]) = v;
        }
    }
    __syncthreads();

    int l = tid & 63, w = tid >> 6;
    int lr = l & 15, lk = l >> 4;
    fx4 acc0[8], acc1[8];
#pragma unroll
    for (int ct = 0; ct < 8; ct++) {
        acc0[ct] = (fx4){0.f, 0.f, 0.f, 0.f};
        acc1[ct] = (fx4){0.f, 0.f, 0.f, 0.f};
    }
#pragma unroll
    for (int kt = 0; kt < 4; kt++) {
        int ch = kt * 4 + lk;
        int n0 = w * 32 + lr, n1 = n0 + 16;
        bfx8 b0 = __builtin_bit_cast(bfx8, *(const s16x8*)(&Ash[n0 * 64 + ((ch ^ (n0 & 7)) << 2)]));
        bfx8 b1 = __builtin_bit_cast(bfx8, *(const s16x8*)(&Ash[n1 * 64 + ((ch ^ (n1 & 7)) << 2)]));
#pragma unroll
        for (int ct = 0; ct < 8; ct++) {
            int c = ct * 16 + lr;
            bfx8 aw = __builtin_bit_cast(bfx8, *(const s16x8*)(&Wsh[c * 64 + ((ch ^ (c & 7)) << 2)]));
            acc0[ct] = __builtin_amdgcn_mfma_f32_16x16x32_bf16(aw, b0, acc0[ct], 0, 0, 0);
            acc1[ct] = __builtin_amdgcn_mfma_f32_16x16x32_bf16(aw, b1, acc1[ct], 0, 0, 0);
        }
    }
    // D: col(lane&15) = node, row((lane>>4)*4+reg) = outcol => 4 consecutive cols/thread
    unsigned int* o = blockIdx.y ? xrb : xlb;
    int g0 = row0 + w * 32 + lr, g1 = g0 + 16;
#pragma unroll
    for (int ct = 0; ct < 8; ct++) {
        int cb = ct * 8 + lk * 2;  // uint index of col base (ct*16 + lk*4)/2
        if (g0 < N_NODES) {
            uint2 p0;
            p0.x = packbf2(acc0[ct][0], acc0[ct][1]);
            p0.y = packbf2(acc0[ct][2], acc0[ct][3]);
            *(uint2*)(o + (size_t)g0 * 64 + cb) = p0;
        }
        if (g1 < N_NODES) {
            uint2 p1;
            p1.x = packbf2(acc1[ct][0], acc1[ct][1]);
            p1.y = packbf2(acc1[ct][2], acc1[ct][3]);
            *(uint2*)(o + (size_t)g1 * 64 + cb) = p1;
        }
    }
}

// ---------------- Edge aggregation: defer-max online softmax, exp2 domain ----------------
__global__ __launch_bounds__(256) void aggregate_kernel(
    const unsigned int* __restrict__ xlb, const unsigned int* __restrict__ xrb,
    const float* __restrict__ att, const float* __restrict__ bias,
    const int* __restrict__ rowptr, const int* __restrict__ csr_src,
    float* __restrict__ hout) {
    int node = blockIdx.x * 8 + (threadIdx.x >> 5);
    if (node >= N_NODES) return;
    int hl = threadIdx.x & 31;
    int c0 = hl * 4;
    float4 a4 = *(const float4*)(att + c0);
    a4.x *= LOG2E; a4.y *= LOG2E; a4.z *= LOG2E; a4.w *= LOG2E;  // exp2 domain
    const uint2 ru = *(const uint2*)(xrb + (size_t)node * 64 + hl * 2);
    float r0 = __uint_as_float(ru.x << 16), r1 = __uint_as_float(ru.x & 0xffff0000u);
    float r2 = __uint_as_float(ru.y << 16), r3 = __uint_as_float(ru.y & 0xffff0000u);
    int beg = rowptr[node], end = rowptr[node + 1];
    float m = -INFINITY, s = 0.f;
    float4 acc = make_float4(0.f, 0.f, 0.f, 0.f);
    for (int base = beg; base < end; base += 8) {
        int nn = end - base;
        if (nn > 8) nn = 8;
        int idx8 = csr_src[min(base + (hl & 7), end - 1)];
        float4 vf[8];
        float p[8];
#pragma unroll
        for (int j = 0; j < 8; j++) {
            int sj = __shfl(idx8, j, 32);
            uint2 u = *(const uint2*)(xlb + (size_t)sj * 64 + hl * 2);
            vf[j].x = __uint_as_float(u.x << 16);
            vf[j].y = __uint_as_float(u.x & 0xffff0000u);
            vf[j].z = __uint_as_float(u.y << 16);
            vf[j].w = __uint_as_float(u.y & 0xffff0000u);
            float s0 = vf[j].x + r0, s1 = vf[j].y + r1;
            float s2 = vf[j].z + r2, s3 = vf[j].w + r3;
            p[j] = fmaxf(s0, NEG * s0) * a4.x + fmaxf(s1, NEG * s1) * a4.y +
                   fmaxf(s2, NEG * s2) * a4.z + fmaxf(s3, NEG * s3) * a4.w;
        }
#pragma unroll
        for (int off = 1; off <= 16; off <<= 1) {
#pragma unroll
            for (int j = 0; j < 8; j++) p[j] += __shfl_xor(p[j], off, 32);
        }
#pragma unroll
        for (int j = 0; j < 8; j++)
            if (j >= nn) p[j] = -INFINITY;
        float pmax = fmaxf(fmaxf(fmaxf(p[0], p[1]), fmaxf(p[2], p[3])),
                           fmaxf(fmaxf(p[4], p[5]), fmaxf(p[6], p[7])));
        if (pmax > m + 8.f) {  // defer-max: rescale only on big jump (first chunk: m=-inf)
            float c = exp2f(m - pmax);
            s *= c;
            acc.x *= c; acc.y *= c; acc.z *= c; acc.w *= c;
            m = pmax;
        }
#pragma unroll
        for (int j = 0; j < 8; j++) {
            float w = exp2f(p[j] - m);  // masked j: exp2(-inf)=0; bounded by 2^8
            s += w;
            acc.x += w * vf[j].x; acc.y += w * vf[j].y;
            acc.z += w * vf[j].z; acc.w += w * vf[j].w;
        }
    }
    float inv = 1.f / s;
    const float4 b4 = *(const float4*)(bias + c0);
    float4 o;
    o.x = acc.x * inv + b4.x; o.y = acc.y * inv + b4.y;
    o.z = acc.z * inv + b4.z; o.w = acc.w * inv + b4.w;
    *(float4*)(hout + (size_t)node * HID + c0) = o;
}

// ---------------- BatchNorm stats ----------------
__global__ __launch_bounds__(256) void bn_reduce_kernel(const float* __restrict__ h,
                                                        float* __restrict__ part) {
    int tid = threadIdx.x;
    int c = tid & 127, half = tid >> 7;
    float s = 0.f, q = 0.f;
    for (int r = blockIdx.x * 2 + half; r < N_NODES; r += RB * 2) {
        float v = h[(size_t)r * HID + c];
        s += v; q += v * v;
    }
    __shared__ float shs[256], shq[256];
    shs[tid] = s; shq[tid] = q;
    __syncthreads();
    if (half == 0) {
        part[blockIdx.x * 256 + c] = s + shs[tid + 128];
        part[blockIdx.x * 256 + 128 + c] = q + shq[tid + 128];
    }
}

__global__ void bn_finalize_kernel(const float* __restrict__ part,
                                   const float* __restrict__ gamma,
                                   const float* __restrict__ beta,
                                   float* __restrict__ scale, float* __restrict__ shift) {
    int c = threadIdx.x;  // 128 threads
    float s = 0.f, q = 0.f;
    for (int b = 0; b < RB; b++) {
        s += part[b * 256 + c];
        q += part[b * 256 + 128 + c];
    }
    float m = s / (float)N_NODES;
    float v = q / (float)N_NODES - m * m;
    if (v < 0.f) v = 0.f;
    float rs = rsqrtf(v + EPS);
    float sc = rs * gamma[c];
    scale[c] = sc;
    shift[c] = beta[c] - m * sc;
}

// Residual accumulate of normalized h (final layer only; earlier layers fused in gemm).
__global__ __launch_bounds__(256) void accb_kernel(const float* __restrict__ h,
                                                   const float* __restrict__ scale,
                                                   const float* __restrict__ shift,
                                                   float* __restrict__ acc) {
    int idx = blockIdx.x * 256 + threadIdx.x;
    if (idx >= N_NODES * HID) return;
    int c = idx & 127;
    float v = h[idx] * scale[c] + shift[c];
    acc[idx] += 0.2f * v;  // resw = 1/(N_LAYERS+1)
}

// ---------------- Decode: per-pair dot product ----------------
__global__ __launch_bounds__(256) void predict_kernel(const float* __restrict__ acc,
                                                      const int* __restrict__ eli,
                                                      float* __restrict__ out) {
    int p = blockIdx.x * 4 + (threadIdx.x >> 6);
    if (p >= 8192) return;
    int lane = threadIdx.x & 63;
    int i = eli[p], j = eli[8192 + p];
    const float2 va = *(const float2*)(acc + (size_t)i * HID + lane * 2);
    const float2 vb = *(const float2*)(acc + (size_t)j * HID + lane * 2);
    float t = va.x * vb.x + va.y * vb.y;
#pragma unroll
    for (int off = 32; off; off >>= 1) t += __shfl_xor(t, off, 64);
    if (lane == 0) out[p] = t;
}

extern "C" void kernel_launch(void* const* d_in, const int* in_sizes, int n_in,
                              void* d_out, int out_size, void* d_ws, size_t ws_size,
                              hipStream_t stream) {
    const float* x = (const float*)d_in[0];
    const int* ei = (const int*)d_in[1];
    const int* eli = (const int*)d_in[2];
    const float* Wl = (const float*)d_in[3];
    const float* Wr = (const float*)d_in[4];
    const float* att = (const float*)d_in[5];
    const float* bias = (const float*)d_in[6];
    const float* gamma = (const float*)d_in[7];
    const float* beta = (const float*)d_in[8];
    float* out = (float*)d_out;

    char* ws = (char*)d_ws;
    size_t off = 0;
    float* hbuf = (float*)(ws + off); off += (size_t)N_NODES * HID * 4;
    float* accb = (float*)(ws + off); off += (size_t)N_NODES * HID * 4;
    unsigned int* xlb = (unsigned int*)(ws + off); off += (size_t)N_NODES * HID * 2;  // bf16
    unsigned int* xrb = (unsigned int*)(ws + off); off += (size_t)N_NODES * HID * 2;  // bf16
    int* rowptr = (int*)(ws + off);   off += ((size_t)(N_NODES + 1) * 4 + 31) & ~31ul;
    int* csr_src = (int*)(ws + off);  off += (size_t)(ET + 8) * 4;
    int* gcnt  = (int*)(ws + off);    off += (size_t)NBUCK * 4;
    int* bcur  = (int*)(ws + off);    off += (size_t)NBUCK * 4;
    int* bbase = (int*)(ws + off);    off += (size_t)(NBUCK + 1) * 4;
    float* part = (float*)(ws + off); off += (size_t)RB * 256 * 4;
    float* scale = (float*)(ws + off); off += 128 * 4;
    float* shift = (float*)(ws + off); off += 128 * 4;
    unsigned short* wt = (unsigned short*)(ws + off); off += (size_t)8 * HID * HID * 2;
    // pairs buffer aliases accb: only live during CSR build, before accb's first write (l=1 gemm)
    unsigned int* pairs = (unsigned int*)accb;

    // One-time: weights -> bf16 transposed [layer][mat][col][k]
    wconv_kernel<<<8, 256, 0, stream>>>(Wl, Wr, wt);

    // CSR build (dst-sorted), bucketed counting sort; topology fixed across layers
    int nablk = (ET + BCHUNK - 1) / BCHUNK;
    bucket_zero_kernel<<<(NBUCK + 255) / 256, 256, 0, stream>>>(gcnt);
    bucket_hist_kernel<<<nablk, 256, 0, stream>>>(ei, gcnt);
    bucket_scan_kernel<<<1, 1024, 0, stream>>>(gcnt, bbase, bcur, rowptr);
    bucket_scatter_kernel<<<nablk, 256, 0, stream>>>(ei, bcur, pairs);
    bucket_sort_kernel<<<NBUCK, 256, 0, stream>>>(pairs, bbase, rowptr, csr_src);

    for (int l = 0; l < N_LAYERS; l++) {
        const float* hin = (l == 0) ? x : hbuf;
        int donorm = (l == 0) ? 0 : 1;
        int accmode = (l == 0) ? 0 : (l == 1 ? 1 : 2);
        gemm_mfma_kernel<<<dim3((N_NODES + 127) / 128, 2), 256, 0, stream>>>(
            hin, wt + (size_t)l * 2 * HID * HID, xlb, xrb, scale, shift, accb,
            donorm, accmode);
        aggregate_kernel<<<(N_NODES + 7) / 8, 256, 0, stream>>>(
            xlb, xrb, att + l * HID, bias + l * HID, rowptr, csr_src, hbuf);
        bn_reduce_kernel<<<RB, 256, 0, stream>>>(hbuf, part);
        bn_finalize_kernel<<<1, 128, 0, stream>>>(part, gamma + l * HID, beta + l * HID,
                                                  scale, shift);
    }
    // last layer's normalized residual (no following gemm to fuse into)
    accb_kernel<<<(N_NODES * HID + 255) / 256, 256, 0, stream>>>(hbuf, scale, shift, accb);
    predict_kernel<<<8192 / 4, 256, 0, stream>>>(accb, eli, out);
}

// Round 9
// 596.431 us; speedup vs baseline: 3.2562x; 1.1677x over previous
//
#include <hip/hip_runtime.h>
#include <hip/hip_bf16.h>
#include <hip/hip_fp16.h>

#define N_NODES 50000
#define N_EDGES 1600000
#define ET (N_EDGES + N_NODES)
#define HID 128
#define N_LAYERS 4
#define EPS 1e-5f
#define NEG 0.2f
#define RB 256     // bn reduce blocks
#define NBUCK 782  // ceil(N_NODES/64)
#define BCHUNK 8192
#define LOG2E 1.44269504088896f

typedef __attribute__((ext_vector_type(8))) short s16x8;
typedef __attribute__((ext_vector_type(8))) __bf16 bfx8;
typedef __attribute__((ext_vector_type(4))) float fx4;
typedef __attribute__((ext_vector_type(2))) _Float16 f16x2;

__device__ __forceinline__ unsigned int packbf2(float a, float b) {
    unsigned int ua = __float_as_uint(a);
    ua = (ua + 0x7fffu + ((ua >> 16) & 1u)) >> 16;
    unsigned int ub = __float_as_uint(b);
    ub = (ub + 0x7fffu + ((ub >> 16) & 1u)) & 0xffff0000u;
    return (ua & 0xffffu) | ub;
}
__device__ __forceinline__ unsigned short bf16r(float a) {
    unsigned int ua = __float_as_uint(a);
    return (unsigned short)((ua + 0x7fffu + ((ua >> 16) & 1u)) >> 16);
}
__device__ __forceinline__ unsigned int packh2(float a, float b) {
    return __builtin_bit_cast(unsigned int, __builtin_amdgcn_cvt_pkrtz(a, b));
}
__device__ __forceinline__ f16x2 packh2v(float a, float b) {
    return __builtin_bit_cast(f16x2, __builtin_amdgcn_cvt_pkrtz(a, b));
}
__device__ __forceinline__ float2 unpackh2(unsigned int u) {
    f16x2 h = __builtin_bit_cast(f16x2, u);
    return make_float2((float)h.x, (float)h.y);
}

// ---------------- CSR build: two-level bucketed counting sort ----------------
__global__ void bucket_zero_kernel(int* __restrict__ gcnt) {
    int i = blockIdx.x * 256 + threadIdx.x;
    if (i < NBUCK) gcnt[i] = 0;
}

__global__ __launch_bounds__(256) void bucket_hist_kernel(const int* __restrict__ ei,
                                                          int* __restrict__ gcnt) {
    __shared__ int h[NBUCK];
    for (int i = threadIdx.x; i < NBUCK; i += 256) h[i] = 0;
    __syncthreads();
    int base = blockIdx.x * BCHUNK;
    int lim = min(base + BCHUNK, ET);
    for (int i = base + threadIdx.x; i < lim; i += 256) {
        int dst = (i < N_EDGES) ? ei[N_EDGES + i] : i - N_EDGES;
        atomicAdd(&h[dst >> 6], 1);
    }
    __syncthreads();
    for (int i = threadIdx.x; i < NBUCK; i += 256)
        if (h[i]) atomicAdd(&gcnt[i], h[i]);
}

__global__ void bucket_scan_kernel(const int* __restrict__ gcnt, int* __restrict__ bbase,
                                   int* __restrict__ bcur, int* __restrict__ rowptr) {
    __shared__ int sh[1024];
    int tid = threadIdx.x;
    int v = (tid < NBUCK) ? gcnt[tid] : 0;
    sh[tid] = v;
    __syncthreads();
    for (int off = 1; off < 1024; off <<= 1) {
        int t = (tid >= off) ? sh[tid - off] : 0;
        __syncthreads();
        sh[tid] += t;
        __syncthreads();
    }
    if (tid < NBUCK) {
        int ex = sh[tid] - v;
        bbase[tid] = ex;
        bcur[tid] = ex;
    }
    if (tid == NBUCK - 1) bbase[NBUCK] = sh[tid];
    if (tid == 0) rowptr[N_NODES] = ET;
}

__global__ __launch_bounds__(256) void bucket_scatter_kernel(const int* __restrict__ ei,
                                                             int* __restrict__ bcur,
                                                             unsigned int* __restrict__ pairs) {
    __shared__ int h[NBUCK];
    __shared__ int rbase[NBUCK];
    for (int i = threadIdx.x; i < NBUCK; i += 256) h[i] = 0;
    __syncthreads();
    int base = blockIdx.x * BCHUNK;
    int lim = min(base + BCHUNK, ET);
    for (int i = base + threadIdx.x; i < lim; i += 256) {
        int dst = (i < N_EDGES) ? ei[N_EDGES + i] : i - N_EDGES;
        atomicAdd(&h[dst >> 6], 1);
    }
    __syncthreads();
    for (int i = threadIdx.x; i < NBUCK; i += 256) {
        rbase[i] = h[i] ? atomicAdd(&bcur[i], h[i]) : 0;
        h[i] = 0;
    }
    __syncthreads();
    for (int i = base + threadIdx.x; i < lim; i += 256) {
        int src, dst;
        if (i < N_EDGES) { src = ei[i]; dst = ei[N_EDGES + i]; }
        else { src = dst = i - N_EDGES; }
        int b = dst >> 6;
        int pos = rbase[b] + atomicAdd(&h[b], 1);
        pairs[pos] = (unsigned int)src | ((unsigned int)(dst & 63) << 16);
    }
}

__global__ __launch_bounds__(256) void bucket_sort_kernel(const unsigned int* __restrict__ pairs,
                                                          const int* __restrict__ bbase,
                                                          int* __restrict__ rowptr,
                                                          int* __restrict__ csr_src) {
    __shared__ int h[64], ex[64], cur[64];
    int b = blockIdx.x;
    int tid = threadIdx.x;
    if (tid < 64) h[tid] = 0;
    __syncthreads();
    int bs = bbase[b], be = bbase[b + 1];
    for (int i = bs + tid; i < be; i += 256) atomicAdd(&h[pairs[i] >> 16], 1);
    __syncthreads();
    if (tid == 0) {
        int run = 0;
        for (int k = 0; k < 64; k++) { ex[k] = run; cur[k] = run; run += h[k]; }
    }
    __syncthreads();
    int n0 = b * 64;
    if (tid < 64 && n0 + tid < N_NODES) rowptr[n0 + tid] = bs + ex[tid];
    for (int i = bs + tid; i < be; i += 256) {
        unsigned int u = pairs[i];
        int ln = u >> 16;
        int pos = bs + atomicAdd(&cur[ln], 1);
        csr_src[pos] = (int)(u & 0xffffu);
    }
}

// ---------------- Weight convert: W[k][c] f32 -> Wt[c][k] bf16, all 8 mats ----------------
__global__ __launch_bounds__(256) void wconv_kernel(const float* __restrict__ Wl,
                                                    const float* __restrict__ Wr,
                                                    unsigned short* __restrict__ wt) {
    int m = blockIdx.x;  // 0..7: layer = m>>1, mat = m&1
    const float* __restrict__ W = ((m & 1) ? Wr : Wl) + (size_t)(m >> 1) * HID * HID;
    unsigned short* __restrict__ o = wt + (size_t)m * HID * HID;
    for (int i = threadIdx.x; i < HID * HID; i += 256) {
        int k = i >> 7, c = i & 127;
        o[c * HID + k] = bf16r(W[i]);
    }
}

// ---------------- MFMA GEMM (swapped operands): y==0 -> xlh, y==1 -> xrh (both f16) ----
// 128 rows x 128 cols per block, 4 waves. A(h, normalized) + Wt in LDS (swizzled).
// hin: f32 (layer 0, hin_f) or f16 (layers 1+, hin_h). accb kept in f16.
__global__ __launch_bounds__(256) void gemm_mfma_kernel(
    const float* __restrict__ hin_f, const unsigned int* __restrict__ hin_h,
    const unsigned short* __restrict__ wt_layer,
    unsigned int* __restrict__ xlh, unsigned int* __restrict__ xrh,
    const float* __restrict__ scale, const float* __restrict__ shift,
    unsigned int* __restrict__ accb, int donorm, int accmode) {
    __shared__ unsigned int Ash[128 * 64];  // 32KB
    __shared__ unsigned int Wsh[128 * 64];  // 32KB
    int row0 = blockIdx.x * 128;
    int tid = threadIdx.x;
    for (int i = tid; i < 2048; i += 256) {
        int r = i >> 4, ch = i & 15;
        int gr = row0 + r;
        uint4 pk = make_uint4(0u, 0u, 0u, 0u);
        if (gr < N_NODES) {
            float4 va, vb;
            if (hin_h) {
                uint4 u = ((const uint4*)(hin_h + (size_t)gr * 64))[ch];
                float2 f0 = unpackh2(u.x), f1 = unpackh2(u.y);
                float2 f2 = unpackh2(u.z), f3 = unpackh2(u.w);
                va = make_float4(f0.x, f0.y, f1.x, f1.y);
                vb = make_float4(f2.x, f2.y, f3.x, f3.y);
            } else {
                const float4* src = (const float4*)(hin_f + (size_t)gr * HID + ch * 8);
                va = src[0]; vb = src[1];
            }
            if (donorm) {
                const float4* s4 = (const float4*)(scale + ch * 8);
                const float4* t4 = (const float4*)(shift + ch * 8);
                float4 s0 = s4[0], s1 = s4[1], t0 = t4[0], t1 = t4[1];
                va.x = va.x * s0.x + t0.x; va.y = va.y * s0.y + t0.y;
                va.z = va.z * s0.z + t0.z; va.w = va.w * s0.w + t0.w;
                vb.x = vb.x * s1.x + t1.x; vb.y = vb.y * s1.y + t1.y;
                vb.z = vb.z * s1.z + t1.z; vb.w = vb.w * s1.w + t1.w;
            }
            if (accmode && blockIdx.y == 0) {
                uint4* ap = (uint4*)(accb + (size_t)gr * 64) + ch;
                uint4 av;
                if (accmode == 1) {
                    av.x = packh2(0.2f * va.x, 0.2f * va.y);
                    av.y = packh2(0.2f * va.z, 0.2f * va.w);
                    av.z = packh2(0.2f * vb.x, 0.2f * vb.y);
                    av.w = packh2(0.2f * vb.z, 0.2f * vb.w);
                } else {
                    uint4 old = *ap;
                    float2 o0 = unpackh2(old.x), o1 = unpackh2(old.y);
                    float2 o2 = unpackh2(old.z), o3 = unpackh2(old.w);
                    av.x = packh2(o0.x + 0.2f * va.x, o0.y + 0.2f * va.y);
                    av.y = packh2(o1.x + 0.2f * va.z, o1.y + 0.2f * va.w);
                    av.z = packh2(o2.x + 0.2f * vb.x, o2.y + 0.2f * vb.y);
                    av.w = packh2(o3.x + 0.2f * vb.z, o3.y + 0.2f * vb.w);
                }
                *ap = av;
            }
            pk.x = packbf2(va.x, va.y); pk.y = packbf2(va.z, va.w);
            pk.z = packbf2(vb.x, vb.y); pk.w = packbf2(vb.z, vb.w);
        }
        *(uint4*)(&Ash[r * 64 + ((ch ^ (r & 7)) << 2)]) = pk;
    }
    {
        const uint4* wm4 = (const uint4*)(wt_layer + (size_t)blockIdx.y * HID * HID);
        for (int i = tid; i < 2048; i += 256) {
            int c = i >> 4, ch = i & 15;
            uint4 v = wm4[i];
            *(uint4*)(&Wsh[c * 64 + ((ch ^ (c & 7)) << 2)]) = v;
        }
    }
    __syncthreads();

    int l = tid & 63, w = tid >> 6;
    int lr = l & 15, lk = l >> 4;
    fx4 acc0[8], acc1[8];
#pragma unroll
    for (int ct = 0; ct < 8; ct++) {
        acc0[ct] = (fx4){0.f, 0.f, 0.f, 0.f};
        acc1[ct] = (fx4){0.f, 0.f, 0.f, 0.f};
    }
#pragma unroll
    for (int kt = 0; kt < 4; kt++) {
        int ch = kt * 4 + lk;
        int n0 = w * 32 + lr, n1 = n0 + 16;
        bfx8 b0 = __builtin_bit_cast(bfx8, *(const s16x8*)(&Ash[n0 * 64 + ((ch ^ (n0 & 7)) << 2)]));
        bfx8 b1 = __builtin_bit_cast(bfx8, *(const s16x8*)(&Ash[n1 * 64 + ((ch ^ (n1 & 7)) << 2)]));
#pragma unroll
        for (int ct = 0; ct < 8; ct++) {
            int c = ct * 16 + lr;
            bfx8 aw = __builtin_bit_cast(bfx8, *(const s16x8*)(&Wsh[c * 64 + ((ch ^ (c & 7)) << 2)]));
            acc0[ct] = __builtin_amdgcn_mfma_f32_16x16x32_bf16(aw, b0, acc0[ct], 0, 0, 0);
            acc1[ct] = __builtin_amdgcn_mfma_f32_16x16x32_bf16(aw, b1, acc1[ct], 0, 0, 0);
        }
    }
    // D: col(lane&15) = node, row((lane>>4)*4+reg) = outcol => 4 consecutive cols/thread
    unsigned int* o = blockIdx.y ? xrh : xlh;
    int g0 = row0 + w * 32 + lr, g1 = g0 + 16;
#pragma unroll
    for (int ct = 0; ct < 8; ct++) {
        int cb = ct * 8 + lk * 2;
        if (g0 < N_NODES) {
            uint2 p0;
            p0.x = packh2(acc0[ct][0], acc0[ct][1]);
            p0.y = packh2(acc0[ct][2], acc0[ct][3]);
            *(uint2*)(o + (size_t)g0 * 64 + cb) = p0;
        }
        if (g1 < N_NODES) {
            uint2 p1;
            p1.x = packh2(acc1[ct][0], acc1[ct][1]);
            p1.y = packh2(acc1[ct][2], acc1[ct][3]);
            *(uint2*)(o + (size_t)g1 * 64 + cb) = p1;
        }
    }
}

// ---------------- Edge aggregation: f16 packed score math + fdot2, defer-max ------------
__global__ __launch_bounds__(256) void aggregate_kernel(
    const unsigned int* __restrict__ xlh, const unsigned int* __restrict__ xrh,
    const float* __restrict__ att, const float* __restrict__ bias,
    const int* __restrict__ rowptr, const int* __restrict__ csr_src,
    unsigned int* __restrict__ hout) {
    int node = blockIdx.x * 8 + (threadIdx.x >> 5);
    if (node >= N_NODES) return;
    int hl = threadIdx.x & 31;
    int c0 = hl * 4;
    float4 a4 = *(const float4*)(att + c0);
    // exp2 domain: fold log2(e) into a
    f16x2 alo = packh2v(a4.x * LOG2E, a4.y * LOG2E);
    f16x2 ahi = packh2v(a4.z * LOG2E, a4.w * LOG2E);
    const uint2 ru = *(const uint2*)(xrh + (size_t)node * 64 + hl * 2);
    f16x2 rlo = __builtin_bit_cast(f16x2, ru.x);
    f16x2 rhi = __builtin_bit_cast(f16x2, ru.y);
    const f16x2 negc = {(_Float16)NEG, (_Float16)NEG};
    int beg = rowptr[node], end = rowptr[node + 1];
    float m = -INFINITY, s = 0.f;
    float4 acc = make_float4(0.f, 0.f, 0.f, 0.f);
    for (int base = beg; base < end; base += 8) {
        int nn = end - base;
        if (nn > 8) nn = 8;
        int idx8 = csr_src[min(base + (hl & 7), end - 1)];
        uint2 v[8];
        float p[8];
#pragma unroll
        for (int j = 0; j < 8; j++) {
            int sj = __shfl(idx8, j, 32);
            v[j] = *(const uint2*)(xlh + (size_t)sj * 64 + hl * 2);
            f16x2 vlo = __builtin_bit_cast(f16x2, v[j].x);
            f16x2 vhi = __builtin_bit_cast(f16x2, v[j].y);
            f16x2 slo = vlo + rlo, shi = vhi + rhi;                 // v_pk_add_f16
            f16x2 mlo = __builtin_elementwise_max(slo, slo * negc); // pk_mul + pk_max
            f16x2 mhi = __builtin_elementwise_max(shi, shi * negc);
            p[j] = __builtin_amdgcn_fdot2(mlo, alo,
                     __builtin_amdgcn_fdot2(mhi, ahi, 0.f, false), false);
        }
        // 8 concurrent butterfly sums over the 32-lane half
#pragma unroll
        for (int off = 1; off <= 16; off <<= 1) {
#pragma unroll
            for (int j = 0; j < 8; j++) p[j] += __shfl_xor(p[j], off, 32);
        }
#pragma unroll
        for (int j = 0; j < 8; j++)
            if (j >= nn) p[j] = -INFINITY;
        float pmax = fmaxf(fmaxf(fmaxf(p[0], p[1]), fmaxf(p[2], p[3])),
                           fmaxf(fmaxf(p[4], p[5]), fmaxf(p[6], p[7])));
        if (pmax > m + 8.f) {  // defer-max (first chunk: m=-inf triggers)
            float c = exp2f(m - pmax);
            s *= c;
            acc.x *= c; acc.y *= c; acc.z *= c; acc.w *= c;
            m = pmax;
        }
#pragma unroll
        for (int j = 0; j < 8; j++) {
            float w = exp2f(p[j] - m);  // masked j: exp2(-inf)=0; bounded by 2^8
            s += w;
            f16x2 vlo = __builtin_bit_cast(f16x2, v[j].x);
            f16x2 vhi = __builtin_bit_cast(f16x2, v[j].y);
            acc.x += w * (float)vlo.x; acc.y += w * (float)vlo.y;   // v_fma_mix
            acc.z += w * (float)vhi.x; acc.w += w * (float)vhi.y;
        }
    }
    float inv = 1.f / s;
    const float4 b4 = *(const float4*)(bias + c0);
    uint2 po;
    po.x = packh2(acc.x * inv + b4.x, acc.y * inv + b4.y);
    po.y = packh2(acc.z * inv + b4.z, acc.w * inv + b4.w);
    *(uint2*)(hout + (size_t)node * 64 + hl * 2) = po;
}

// ---------------- BatchNorm stats (h in f16) ----------------
__global__ __launch_bounds__(256) void bn_reduce_kernel(const unsigned int* __restrict__ h,
                                                        float* __restrict__ part) {
    int tid = threadIdx.x;
    int cu = tid & 63, half = tid >> 6;  // cu: uint col (2 channels), 4 row-groups
    float s0 = 0.f, q0 = 0.f, s1 = 0.f, q1 = 0.f;
    for (int r = blockIdx.x * 4 + half; r < N_NODES; r += RB * 4) {
        float2 v = unpackh2(h[(size_t)r * 64 + cu]);
        s0 += v.x; q0 += v.x * v.x;
        s1 += v.y; q1 += v.y * v.y;
    }
    __shared__ float sh[256];
    sh[half * 64 + cu] = s0;
    __syncthreads();
    if (tid < 64) {
        float r0 = sh[tid] + sh[64 + tid] + sh[128 + tid] + sh[192 + tid];
        part[blockIdx.x * 256 + tid * 2] = r0;
    }
    __syncthreads();
    sh[half * 64 + cu] = q0;
    __syncthreads();
    if (tid < 64) {
        float r0 = sh[tid] + sh[64 + tid] + sh[128 + tid] + sh[192 + tid];
        part[blockIdx.x * 256 + 128 + tid * 2] = r0;
    }
    __syncthreads();
    sh[half * 64 + cu] = s1;
    __syncthreads();
    if (tid < 64) {
        float r0 = sh[tid] + sh[64 + tid] + sh[128 + tid] + sh[192 + tid];
        part[blockIdx.x * 256 + tid * 2 + 1] = r0;
    }
    __syncthreads();
    sh[half * 64 + cu] = q1;
    __syncthreads();
    if (tid < 64) {
        float r0 = sh[tid] + sh[64 + tid] + sh[128 + tid] + sh[192 + tid];
        part[blockIdx.x * 256 + 128 + tid * 2 + 1] = r0;
    }
}

__global__ void bn_finalize_kernel(const float* __restrict__ part,
                                   const float* __restrict__ gamma,
                                   const float* __restrict__ beta,
                                   float* __restrict__ scale, float* __restrict__ shift) {
    int c = threadIdx.x;  // 128 threads
    float s = 0.f, q = 0.f;
    for (int b = 0; b < RB; b++) {
        s += part[b * 256 + c];
        q += part[b * 256 + 128 + c];
    }
    float m = s / (float)N_NODES;
    float v = q / (float)N_NODES - m * m;
    if (v < 0.f) v = 0.f;
    float rs = rsqrtf(v + EPS);
    float sc = rs * gamma[c];
    scale[c] = sc;
    shift[c] = beta[c] - m * sc;
}

// Residual accumulate of normalized h (final layer only; earlier layers fused in gemm).
__global__ __launch_bounds__(256) void accb_kernel(const unsigned int* __restrict__ h,
                                                   const float* __restrict__ scale,
                                                   const float* __restrict__ shift,
                                                   unsigned int* __restrict__ acc) {
    int idx = blockIdx.x * 256 + threadIdx.x;
    if (idx >= N_NODES * 64) return;
    int c = (idx & 63) * 2;
    float2 v = unpackh2(h[idx]);
    float n0 = v.x * scale[c] + shift[c];
    float n1 = v.y * scale[c + 1] + shift[c + 1];
    float2 a = unpackh2(acc[idx]);
    acc[idx] = packh2(a.x + 0.2f * n0, a.y + 0.2f * n1);
}

// ---------------- Decode: per-pair dot product (acc in f16) ----------------
__global__ __launch_bounds__(256) void predict_kernel(const unsigned int* __restrict__ acc,
                                                      const int* __restrict__ eli,
                                                      float* __restrict__ out) {
    int p = blockIdx.x * 4 + (threadIdx.x >> 6);
    if (p >= 8192) return;
    int lane = threadIdx.x & 63;
    int i = eli[p], j = eli[8192 + p];
    f16x2 va = __builtin_bit_cast(f16x2, acc[(size_t)i * 64 + lane]);
    f16x2 vb = __builtin_bit_cast(f16x2, acc[(size_t)j * 64 + lane]);
    float t = (float)va.x * (float)vb.x + (float)va.y * (float)vb.y;
#pragma unroll
    for (int off = 32; off; off >>= 1) t += __shfl_xor(t, off, 64);
    if (lane == 0) out[p] = t;
}

extern "C" void kernel_launch(void* const* d_in, const int* in_sizes, int n_in,
                              void* d_out, int out_size, void* d_ws, size_t ws_size,
                              hipStream_t stream) {
    const float* x = (const float*)d_in[0];
    const int* ei = (const int*)d_in[1];
    const int* eli = (const int*)d_in[2];
    const float* Wl = (const float*)d_in[3];
    const float* Wr = (const float*)d_in[4];
    const float* att = (const float*)d_in[5];
    const float* bias = (const float*)d_in[6];
    const float* gamma = (const float*)d_in[7];
    const float* beta = (const float*)d_in[8];
    float* out = (float*)d_out;

    char* ws = (char*)d_ws;
    size_t off = 0;
    unsigned int* hbuf = (unsigned int*)(ws + off); off += (size_t)N_NODES * HID * 2;  // f16
    unsigned int* accb = (unsigned int*)(ws + off); off += (size_t)N_NODES * HID * 2;  // f16
    unsigned int* xlh  = (unsigned int*)(ws + off); off += (size_t)N_NODES * HID * 2;  // f16
    unsigned int* xrh  = (unsigned int*)(ws + off); off += (size_t)N_NODES * HID * 2;  // f16
    int* rowptr = (int*)(ws + off);   off += ((size_t)(N_NODES + 1) * 4 + 31) & ~31ul;
    int* csr_src = (int*)(ws + off);  off += (size_t)(ET + 8) * 4;
    int* gcnt  = (int*)(ws + off);    off += (size_t)NBUCK * 4;
    int* bcur  = (int*)(ws + off);    off += (size_t)NBUCK * 4;
    int* bbase = (int*)(ws + off);    off += (size_t)(NBUCK + 1) * 4;
    float* part = (float*)(ws + off); off += (size_t)RB * 256 * 4;
    float* scale = (float*)(ws + off); off += 128 * 4;
    float* shift = (float*)(ws + off); off += 128 * 4;
    unsigned short* wt = (unsigned short*)(ws + off); off += (size_t)8 * HID * HID * 2;
    unsigned int* pairs = (unsigned int*)(ws + off); off += (size_t)ET * 4;  // CSR temp

    // One-time: weights -> bf16 transposed [layer][mat][col][k]
    wconv_kernel<<<8, 256, 0, stream>>>(Wl, Wr, wt);

    // CSR build (dst-sorted), bucketed counting sort; topology fixed across layers
    int nablk = (ET + BCHUNK - 1) / BCHUNK;
    bucket_zero_kernel<<<(NBUCK + 255) / 256, 256, 0, stream>>>(gcnt);
    bucket_hist_kernel<<<nablk, 256, 0, stream>>>(ei, gcnt);
    bucket_scan_kernel<<<1, 1024, 0, stream>>>(gcnt, bbase, bcur, rowptr);
    bucket_scatter_kernel<<<nablk, 256, 0, stream>>>(ei, bcur, pairs);
    bucket_sort_kernel<<<NBUCK, 256, 0, stream>>>(pairs, bbase, rowptr, csr_src);

    for (int l = 0; l < N_LAYERS; l++) {
        int donorm = (l == 0) ? 0 : 1;
        int accmode = (l == 0) ? 0 : (l == 1 ? 1 : 2);
        gemm_mfma_kernel<<<dim3((N_NODES + 127) / 128, 2), 256, 0, stream>>>(
            (l == 0) ? x : nullptr, (l == 0) ? nullptr : hbuf,
            wt + (size_t)l * 2 * HID * HID, xlh, xrh, scale, shift, accb,
            donorm, accmode);
        aggregate_kernel<<<(N_NODES + 7) / 8, 256, 0, stream>>>(
            xlh, xrh, att + l * HID, bias + l * HID, rowptr, csr_src, hbuf);
        bn_reduce_kernel<<<RB, 256, 0, stream>>>(hbuf, part);
        bn_finalize_kernel<<<1, 128, 0, stream>>>(part, gamma + l * HID, beta + l * HID,
                                                  scale, shift);
    }
    // last layer's normalized residual (no following gemm to fuse into)
    accb_kernel<<<(N_NODES * 64 + 255) / 256, 256, 0, stream>>>(hbuf, scale, shift, accb);
    predict_kernel<<<8192 / 4, 256, 0, stream>>>(accb, eli, out);
}